// Round 19
// baseline (217.419 us; speedup 1.0000x reference)
//
#include <hip/hip_runtime.h>
#include <hip/hip_bf16.h>

// Problem constants
#define DM     128
#define DSTATE 16
#define DINNER 256
#define CCONV  16
#define NEIGH  27
#define DSEQ   432   // CCONV * NEIGH
#define DTRANK 14
#define LVOL   4096  // 16*16*16
#define BATCH  2
#define NTOK   8192  // BATCH * LVOL

typedef __attribute__((ext_vector_type(8))) unsigned short ushort8_t;

__device__ __forceinline__ float bf2f(unsigned short u) {
    union { unsigned int i; float f; } v; v.i = ((unsigned int)u) << 16; return v.f;
}
__device__ __forceinline__ unsigned short f2b(float f) {
    __hip_bfloat16 hb = __float2bfloat16(f);
    return *(unsigned short*)&hb;
}

// ---------------------------------------------------------------- merged weight prep
__global__ void k_wprep(const float* __restrict__ w_in, const float* __restrict__ w_fold,
                        const float* __restrict__ w_out, float2* __restrict__ wint2,
                        float* __restrict__ wft2, float* __restrict__ wot2) {
    int idx = blockIdx.x * 256 + threadIdx.x;
    if (idx < 32768) {
        int j = idx >> 8, t = idx & 255;
        wint2[idx] = make_float2(w_in[t * 128 + j], w_in[(t + 256) * 128 + j]);
    } else if (idx < 32768 + 110592) {
        int local = idx - 32768;
        int t = local / 432, d = local - t * 432;
        wft2[(d >> 1) * 512 + t * 2 + (d & 1)] = w_fold[t * 432 + d];
    } else if (idx < 32768 + 110592 + 32768) {
        int local = idx - 32768 - 110592;
        int o = local >> 8, i = local & 255;
        wot2[(i >> 1) * 256 + o * 2 + (i & 1)] = w_out[o * 256 + i];
    }
}

// ---------------------------------------------------------------- in-proj GEMM
__global__ void k_inproj(const float* __restrict__ x, const float2* __restrict__ wint2,
                         float* __restrict__ xpt, float* __restrict__ zbuf) {
    int t = threadIdx.x;
    int tokbase = blockIdx.x * 16;
    int b = tokbase >> 12, lb = tokbase & 4095;
    __shared__ float xs_[16][128];
    for (int idx = t; idx < 2048; idx += 256)
        xs_[idx >> 7][idx & 127] = x[tokbase * 128 + idx];
    __syncthreads();
    float a0[16], a1[16];
#pragma unroll
    for (int k = 0; k < 16; k++) { a0[k] = 0.f; a1[k] = 0.f; }
    for (int j = 0; j < 128; j += 4) {
        float2 w0 = wint2[(j + 0) * 256 + t];
        float2 w1 = wint2[(j + 1) * 256 + t];
        float2 w2 = wint2[(j + 2) * 256 + t];
        float2 w3 = wint2[(j + 3) * 256 + t];
#pragma unroll
        for (int k = 0; k < 16; k++) {
            float4 xv = *(const float4*)&xs_[k][j];
            a0[k] += xv.x * w0.x + xv.y * w1.x + xv.z * w2.x + xv.w * w3.x;
            a1[k] += xv.x * w0.y + xv.y * w1.y + xv.z * w2.y + xv.w * w3.y;
        }
    }
    float* xr = xpt + (size_t)(b * 256 + t) * 4096 + lb;
#pragma unroll
    for (int k = 0; k < 16; k++) xr[k] = a0[k];
#pragma unroll
    for (int k = 0; k < 16; k++) zbuf[(tokbase + k) * 256 + t] = a1[k];
}

// ---------------------------------------------------------------- grouped conv3d + SiLU
__global__ void k_conv(const float* __restrict__ xpt, const float* __restrict__ conv_w,
                       const float* __restrict__ conv_b, float* __restrict__ xc) {
    int t = threadIdx.x;
    int tok = blockIdx.x * 256 + t;
    int co = blockIdx.y;
    int b = tok >> 12, l = tok & 4095;
    int d0 = l >> 8, h0 = (l >> 4) & 15, w0 = l & 15;
    __shared__ float wl[432];
    for (int i = t; i < 432; i += 256) wl[i] = conv_w[co * 432 + i];  // [q][27]
    __syncthreads();
    int nbo[27];
#pragma unroll
    for (int t27 = 0; t27 < 27; t27++) {
        int di = t27 / 9 - 1, dj = (t27 / 3) % 3 - 1, dk = t27 % 3 - 1;
        int zd = d0 + di, zh = h0 + dj, zw = w0 + dk;
        nbo[t27] = ((unsigned)zd > 15u || (unsigned)zh > 15u || (unsigned)zw > 15u)
                   ? -1 : ((zd << 8) + (zh << 4) + zw);
    }
    const float* xb = xpt + (size_t)(b * 256 + co * 16) * 4096;
    float acc0 = conv_b[co], acc1 = 0.f;
    for (int t27 = 0; t27 < 27; t27++) {
        int o = nbo[t27];
        if (o >= 0) {
#pragma unroll
            for (int q = 0; q < 16; q += 2) {
                acc0 += xb[q * 4096 + o]       * wl[q * 27 + t27];
                acc1 += xb[(q + 1) * 4096 + o] * wl[(q + 1) * 27 + t27];
            }
        }
    }
    float acc = acc0 + acc1;
    acc = acc / (1.f + __expf(-acc));  // SiLU
    xc[(b * 16 + co) * 4096 + l] = acc;
}

// ---------------------------------------------------------------- x_dbl = x_proj_w @ unfold(xc)
// TWO channels per block (c, c+23): gather shared, two LDS weight rows.
__global__ void k_xdbl(const float* __restrict__ xc, const float* __restrict__ x_proj_w,
                       float* __restrict__ dts, __hip_bfloat16* __restrict__ bc2) {
    int t = threadIdx.x;
    int tok = blockIdx.x * 256 + t;
    int c0 = blockIdx.y;          // 0..22
    int c1 = c0 + 23;             // 23..45
    int b = tok >> 12, l = tok & 4095;
    int d0 = l >> 8, h0 = (l >> 4) & 15, w0 = l & 15;
    __shared__ float wl0[432], wl1[432];
    for (int i = t; i < 432; i += 256) {
        wl0[i] = x_proj_w[c0 * 432 + i];
        wl1[i] = x_proj_w[c1 * 432 + i];
    }
    __syncthreads();
    int nbo[27];
#pragma unroll
    for (int t27 = 0; t27 < 27; t27++) {
        int di = t27 / 9 - 1, dj = (t27 / 3) % 3 - 1, dk = t27 % 3 - 1;
        int zd = d0 + di, zh = h0 + dj, zw = w0 + dk;
        nbo[t27] = ((unsigned)zd > 15u || (unsigned)zh > 15u || (unsigned)zw > 15u)
                   ? -1 : ((zd << 8) + (zh << 4) + zw);
    }
    const float* xcb = xc + b * 16 * 4096;
    float a00 = 0.f, a01 = 0.f, a10 = 0.f, a11 = 0.f;
    for (int t27 = 0; t27 < 27; t27++) {
        int o = nbo[t27];
        if (o >= 0) {
#pragma unroll
            for (int ch = 0; ch < 16; ch += 2) {
                float v0 = xcb[ch * 4096 + o];
                float v1 = xcb[(ch + 1) * 4096 + o];
                int i0 = ch * 27 + t27, i1 = (ch + 1) * 27 + t27;
                a00 += v0 * wl0[i0];
                a01 += v1 * wl0[i1];
                a10 += v0 * wl1[i0];
                a11 += v1 * wl1[i1];
            }
        }
    }
    float acc0 = a00 + a01;
    float acc1 = a10 + a11;
    if (c0 < 14)
        dts[(size_t)(b * 14 + c0) * 4096 + l] = acc0;
    else
        bc2[(size_t)(b * 32 + (c0 - 14)) * 4096 + l] = __float2bfloat16(acc0);
    bc2[(size_t)(b * 32 + (c1 - 14)) * 4096 + l] = __float2bfloat16(acc1);
}

// ---------------------------------------------------------------- selective scan (+ fused delta)
// R16 kernel: monoid (sdt, Bp[16]) fast path, 17 shuffled values/step;
// fallback exact path kept. Output y now stored bf16 (single 16B store).
__global__ __launch_bounds__(512, 2) void k_scan(
        const float* __restrict__ xc, const float* __restrict__ dts,
        const unsigned short* __restrict__ bc2, const float* __restrict__ dt_w,
        const float* __restrict__ dt_b, const float* __restrict__ A_logs,
        const float* __restrict__ Ds, unsigned short* __restrict__ y) {
    int bd = blockIdx.x;
    int b = bd / 432, dch = bd % 432;
    int t = threadIdx.x;               // 0..511
    int lane = t & 63, wv = t >> 6;    // 8 waves

    bool intA = true;
#pragma unroll
    for (int n = 0; n < 16; n++) {
        float An = -__expf(A_logs[dch * 16 + n]);
        intA = intA && (fabsf(An + (float)(n + 1)) < 1e-3f);
    }
    float Dskip = Ds[dch];

    int cch = dch / 27, t27 = dch % 27;
    int di = t27 / 9 - 1, dj = (t27 / 3) % 3 - 1, dk = t27 % 3 - 1;

    // ---- fused delta: softplus(sum_r dts[b][r][l]*dt_w[dch][r] + dt_b[dch])
    float dtv[8];
    {
        float s[8];
        float bias = dt_b[dch];
#pragma unroll
        for (int i = 0; i < 8; i++) s[i] = bias;
        const float* dsb = dts + (size_t)(b * 14) * 4096 + t * 8;
#pragma unroll
        for (int r = 0; r < 14; r++) {
            float d8[8];
            *(float4*)&d8[0] = *(const float4*)(dsb + (size_t)r * 4096);
            *(float4*)&d8[4] = *(const float4*)(dsb + (size_t)r * 4096 + 4);
            float w = dt_w[dch * 14 + r];
#pragma unroll
            for (int i = 0; i < 8; i++) s[i] += d8[i] * w;
        }
#pragma unroll
        for (int i = 0; i < 8; i++)
            dtv[i] = (s[i] > 15.f) ? s[i] : log1pf(__expf(s[i]));
    }

    // ---- u gather; ys pre-init with Dskip*u
    int d0 = t >> 5, h0 = (t >> 1) & 15, w0 = (t & 1) << 3;
    int zd = d0 + di, zh = h0 + dj;
    bool rowok = ((unsigned)zd <= 15u) && ((unsigned)zh <= 15u);
    const float* xr = xc + (size_t)(b * 16 + cch) * 4096 + (zd << 8) + (zh << 4);
    float dtu[8], ys[8];
#pragma unroll
    for (int i = 0; i < 8; i++) {
        int zw = w0 + i + dk;
        float u = (rowok && (unsigned)zw <= 15u) ? xr[zw] : 0.f;
        dtu[i] = dtv[i] * u;
        ys[i] = Dskip * u;
    }

    const unsigned short* bcb = bc2 + (size_t)(b * 32) * 4096 + t * 8;

    __shared__ float waggA[8][16], waggB[8][16];
    __shared__ float waggS[8];

    float h[16];
    float av[8];

    if (intA) {
        // ======================= FAST PATH =======================
        float aw[8];
#pragma unroll
        for (int i = 0; i < 8; i++) { av[i] = __expf(-dtv[i]); aw[i] = av[i]; }
        float sdt = ((dtv[0] + dtv[1]) + (dtv[2] + dtv[3]))
                  + ((dtv[4] + dtv[5]) + (dtv[6] + dtv[7]));

        // pass 1: Bp only (no Ap array); B prefetched 1-deep
        float Bp[16];
        {
            ushort8_t Bnx = *(const ushort8_t*)(bcb);
#pragma unroll
            for (int n = 0; n < 16; n++) {
                ushort8_t Bv = Bnx;
                if (n < 15) Bnx = *(const ushort8_t*)(bcb + (size_t)(n + 1) * 4096);
                float bp = 0.f;
#pragma unroll
                for (int i = 0; i < 8; i++)
                    bp = aw[i] * bp + dtu[i] * bf2f(Bv[i]);
                Bp[n] = bp;
                if (n < 15) {
#pragma unroll
                    for (int i = 0; i < 8; i++) aw[i] *= av[i];
                }
            }
        }

        // wave-level inclusive scan over (sdt, Bp[16])
#pragma unroll
        for (int s = 1; s < 64; s <<= 1) {
            float psdt = __shfl_up(sdt, s, 64);
            float pl = __expf(-sdt);   // later-segment decay base (before update)
            float pb[16];
#pragma unroll
            for (int n = 0; n < 16; n++) pb[n] = __shfl_up(Bp[n], s, 64);
            if (lane >= s) {
                float pw = pl;
#pragma unroll
                for (int n = 0; n < 16; n++) {
                    Bp[n] = pw * pb[n] + Bp[n];
                    pw *= pl;
                }
                sdt += psdt;
            }
        }

        // cross-wave prefix via tiny LDS
        if (lane == 63) {
            waggS[wv] = sdt;
#pragma unroll
            for (int n = 0; n < 16; n++) waggB[wv][n] = Bp[n];
        }
        __syncthreads();

        float exsdt = __shfl_up(sdt, 1, 64);
        float exB[16];
#pragma unroll
        for (int n = 0; n < 16; n++) exB[n] = __shfl_up(Bp[n], 1, 64);
        if (lane == 0) {
            exsdt = 0.f;
#pragma unroll
            for (int n = 0; n < 16; n++) exB[n] = 0.f;
        }
        float WB[16];
#pragma unroll
        for (int n = 0; n < 16; n++) WB[n] = 0.f;
        for (int ww = 0; ww < wv; ww++) {
            float plw = __expf(-waggS[ww]);
            float pww = plw;
#pragma unroll
            for (int n = 0; n < 16; n++) {
                WB[n] = pww * WB[n] + waggB[ww][n];
                pww *= plw;
            }
        }
        float pex = __expf(-exsdt);
        float pwx = pex;
#pragma unroll
        for (int n = 0; n < 16; n++) {
            h[n] = pwx * WB[n] + exB[n];
            pwx *= pex;
        }
    } else {
        // ======================= FALLBACK (exact) =======================
        float A[16];
#pragma unroll
        for (int n = 0; n < 16; n++) A[n] = -__expf(A_logs[dch * 16 + n]);
        float Ap[16], Bp[16];
        ushort8_t Bnx = *(const ushort8_t*)(bcb);
#pragma unroll
        for (int n = 0; n < 16; n++) {
            ushort8_t Bv = Bnx;
            if (n < 15) Bnx = *(const ushort8_t*)(bcb + (size_t)(n + 1) * 4096);
            float ap = 1.f, bp = 0.f, An = A[n];
#pragma unroll
            for (int i = 0; i < 8; i++) {
                float a = __expf(dtv[i] * An);
                bp = a * bp + dtu[i] * bf2f(Bv[i]);
                ap *= a;
            }
            Ap[n] = ap; Bp[n] = bp;
        }
#pragma unroll
        for (int s = 1; s < 64; s <<= 1) {
#pragma unroll
            for (int n = 0; n < 16; n++) {
                float pa = __shfl_up(Ap[n], s, 64);
                float pb = __shfl_up(Bp[n], s, 64);
                if (lane >= s) {
                    Bp[n] = Ap[n] * pb + Bp[n];
                    Ap[n] *= pa;
                }
            }
        }
        if (lane == 63) {
#pragma unroll
            for (int n = 0; n < 16; n++) { waggA[wv][n] = Ap[n]; waggB[wv][n] = Bp[n]; }
        }
        __syncthreads();
#pragma unroll
        for (int n = 0; n < 16; n++) {
            float exA = __shfl_up(Ap[n], 1, 64);
            float exB = __shfl_up(Bp[n], 1, 64);
            if (lane == 0) { exA = 1.f; exB = 0.f; }
            float WB = 0.f;
            for (int ww = 0; ww < wv; ww++)
                WB = waggA[ww][n] * WB + waggB[ww][n];
            h[n] = exA * WB + exB;
        }
    }

    // ---- pass 2: rescan with incoming state; B,C prefetched 1-deep
    if (intA) {
        float aw[8];
#pragma unroll
        for (int i = 0; i < 8; i++) aw[i] = av[i];
        ushort8_t Bnx = *(const ushort8_t*)(bcb);
        ushort8_t Cnx = *(const ushort8_t*)(bcb + (size_t)16 * 4096);
#pragma unroll
        for (int n = 0; n < 16; n++) {
            ushort8_t Bv = Bnx, Cv = Cnx;
            if (n < 15) {
                Bnx = *(const ushort8_t*)(bcb + (size_t)(n + 1) * 4096);
                Cnx = *(const ushort8_t*)(bcb + (size_t)(17 + n) * 4096);
            }
            float hn = h[n];
#pragma unroll
            for (int i = 0; i < 8; i++) {
                hn = aw[i] * hn + dtu[i] * bf2f(Bv[i]);
                ys[i] += hn * bf2f(Cv[i]);
            }
            if (n < 15) {
#pragma unroll
                for (int i = 0; i < 8; i++) aw[i] *= av[i];
            }
        }
    } else {
        ushort8_t Bnx = *(const ushort8_t*)(bcb);
        ushort8_t Cnx = *(const ushort8_t*)(bcb + (size_t)16 * 4096);
#pragma unroll
        for (int n = 0; n < 16; n++) {
            float An = -__expf(A_logs[dch * 16 + n]);
            ushort8_t Bv = Bnx, Cv = Cnx;
            if (n < 15) {
                Bnx = *(const ushort8_t*)(bcb + (size_t)(n + 1) * 4096);
                Cnx = *(const ushort8_t*)(bcb + (size_t)(17 + n) * 4096);
            }
            float hn = h[n];
#pragma unroll
            for (int i = 0; i < 8; i++) {
                float a = __expf(dtv[i] * An);
                hn = a * hn + dtu[i] * bf2f(Bv[i]);
                ys[i] += hn * bf2f(Cv[i]);
            }
        }
    }

    // ---- store y as bf16 (one 16B store)
    unsigned short* yo = y + (size_t)(b * 432 + dch) * 4096 + t * 8;
    ushort8_t o8;
#pragma unroll
    for (int i = 0; i < 8; i++) o8[i] = f2b(ys[i]);
    *(ushort8_t*)yo = o8;
}

// ---------------------------------------------------------------- fold GEMM + LN + gate + out GEMM
// bf16 LDS datapath: ysb[432][16] + vsb[256][16] bf16 (22KB). Fold reads 4
// b128/iter (was 8), out reads 2 (was 4) -> ~45% fewer per-CU LDS slots.
__global__ void k_tail(const unsigned short* __restrict__ y, const float* __restrict__ zbuf,
                       const float2* __restrict__ wft2, const float* __restrict__ ln_g,
                       const float* __restrict__ ln_b, const float2* __restrict__ wot2,
                       float* __restrict__ out) {
    int t = threadIdx.x;
    int tokbase = blockIdx.x * 16;
    int b = tokbase >> 12, lbase = tokbase & 4095;
    __shared__ unsigned short ysb[432][16];   // 13.8 KB
    __shared__ unsigned short vsb[256][16];   // 8 KB
    __shared__ float mu_s[16], rs_s[16];

    for (int idx = t; idx < 432 * 16; idx += 256) {
        int d = idx >> 4, tk = idx & 15;
        ysb[d][tk] = y[(size_t)(b * 432 + d) * 4096 + lbase + tk];
    }
    __syncthreads();

    // fold GEMM: 2 d-rows per iteration; 4 bf16 b128 reads per iter
    float acc[16];
#pragma unroll
    for (int k = 0; k < 16; k++) acc[k] = 0.f;
    for (int d2 = 0; d2 < 216; d2++) {
        float2 w2 = wft2[d2 * 256 + t];
        ushort8_t r0a = *(const ushort8_t*)&ysb[2 * d2][0];
        ushort8_t r0b = *(const ushort8_t*)&ysb[2 * d2][8];
        ushort8_t r1a = *(const ushort8_t*)&ysb[2 * d2 + 1][0];
        ushort8_t r1b = *(const ushort8_t*)&ysb[2 * d2 + 1][8];
#pragma unroll
        for (int k = 0; k < 8; k++)
            acc[k] += w2.x * bf2f(r0a[k]) + w2.y * bf2f(r1a[k]);
#pragma unroll
        for (int k = 0; k < 8; k++)
            acc[8 + k] += w2.x * bf2f(r0b[k]) + w2.y * bf2f(r1b[k]);
    }
    // stash fold output (bf16) for LN stats + out GEMM
#pragma unroll
    for (int k = 0; k < 16; k++) vsb[t][k] = f2b(acc[k]);
    __syncthreads();

    {   // LN stats: token tk = t>>4, 16 threads reduce 256 entries
        int tk = t >> 4, sub = t & 15;
        float s = 0.f, s2 = 0.f;
        for (int m = 0; m < 16; m++) {
            float v = bf2f(vsb[sub * 16 + m][tk]);
            s += v; s2 += v * v;
        }
        s  += __shfl_xor(s, 1, 64);  s2 += __shfl_xor(s2, 1, 64);
        s  += __shfl_xor(s, 2, 64);  s2 += __shfl_xor(s2, 2, 64);
        s  += __shfl_xor(s, 4, 64);  s2 += __shfl_xor(s2, 4, 64);
        s  += __shfl_xor(s, 8, 64);  s2 += __shfl_xor(s2, 8, 64);
        if (sub == 0) {
            float mu = s * (1.f / 256.f);
            float var = s2 * (1.f / 256.f) - mu * mu;
            mu_s[tk] = mu;
            rs_s[tk] = rsqrtf(var + 1e-5f);
        }
    }
    __syncthreads();

    float g = ln_g[t], be = ln_b[t];
#pragma unroll
    for (int k = 0; k < 16; k++) {
        float zv = zbuf[(tokbase + k) * 256 + t];
        float sz = zv / (1.f + __expf(-zv));  // SiLU(z)
        vsb[t][k] = f2b(((acc[k] - mu_s[k]) * rs_s[k] * g + be) * sz);
    }
    __syncthreads();

    // out GEMM: 2 i-rows per iteration; 2 bf16 b128 reads per iter
    float oacc[8];
#pragma unroll
    for (int k = 0; k < 8; k++) oacc[k] = 0.f;
    int o = t & 127, kh = (t >> 7) * 8;
    for (int i2 = 0; i2 < 128; i2++) {
        float2 w2 = wot2[i2 * 128 + o];
        ushort8_t v0 = *(const ushort8_t*)&vsb[2 * i2][kh];
        ushort8_t u0 = *(const ushort8_t*)&vsb[2 * i2 + 1][kh];
#pragma unroll
        for (int k = 0; k < 8; k++)
            oacc[k] += w2.x * bf2f(v0[k]) + w2.y * bf2f(u0[k]);
    }
#pragma unroll
    for (int k = 0; k < 8; k++)
        out[(tokbase + kh + k) * 128 + o] = oacc[k];
}

// ---------------------------------------------------------------- launch
extern "C" void kernel_launch(void* const* d_in, const int* in_sizes, int n_in,
                              void* d_out, int out_size, void* d_ws, size_t ws_size,
                              hipStream_t stream) {
    const float* x        = (const float*)d_in[0];
    const float* w_in     = (const float*)d_in[1];
    const float* conv_w   = (const float*)d_in[2];
    const float* conv_b   = (const float*)d_in[3];
    const float* x_proj_w = (const float*)d_in[4];
    const float* dt_w     = (const float*)d_in[5];
    const float* dt_b     = (const float*)d_in[6];
    const float* A_logs   = (const float*)d_in[7];
    const float* Ds       = (const float*)d_in[8];
    const float* w_fold   = (const float*)d_in[9];
    const float* ln_g     = (const float*)d_in[10];
    const float* ln_b     = (const float*)d_in[11];
    const float* w_out    = (const float*)d_in[12];
    float* out = (float*)d_out;

    float* ws     = (float*)d_ws;
    float* xpt    = ws;                    // B*256*L       = 2,097,152
    float* zbuf   = xpt    + 2097152;      // NTOK*256      = 2,097,152
    float* xc     = zbuf   + 2097152;      // B*16*L        =   131,072
    float* dts    = xc     + 131072;       // B*14*L        =   114,688
    float* bc2    = dts    + 114688;       // B*32*L bf16   (slot float-sized)
    float* ybuf   = bc2    + 262144;       // B*432*L bf16  (slot float-sized)
    float* wint   = ybuf   + 3538944;      // 128*256 float2 =   65,536
    float* wft    = wint   + 65536;        // 432*256       =   110,592
    float* wot    = wft    + 110592;       // 256*128       =    32,768

    k_wprep<<<dim3(688), dim3(256), 0, stream>>>(w_in, w_fold, w_out,
                                                 (float2*)wint, wft, wot);
    k_inproj<<<dim3(NTOK / 16), dim3(256), 0, stream>>>(x, (const float2*)wint, xpt, zbuf);
    k_conv<<<dim3(NTOK / 256, CCONV), dim3(256), 0, stream>>>(xpt, conv_w, conv_b, xc);
    k_xdbl<<<dim3(NTOK / 256, 23), dim3(256), 0, stream>>>(xc, x_proj_w, dts, (__hip_bfloat16*)bc2);
    k_scan<<<dim3(BATCH * DSEQ), dim3(512), 0, stream>>>(xc, dts, (const unsigned short*)bc2,
                                                         dt_w, dt_b, A_logs, Ds,
                                                         (unsigned short*)ybuf);
    k_tail<<<dim3(NTOK / 16), dim3(256), 0, stream>>>((const unsigned short*)ybuf, zbuf,
                                                      (const float2*)wft, ln_g, ln_b,
                                                      (const float2*)wot, out);
}

// Round 20
// 214.120 us; speedup vs baseline: 1.0154x; 1.0154x over previous
//
#include <hip/hip_runtime.h>
#include <hip/hip_bf16.h>

// Problem constants
#define DM     128
#define DSTATE 16
#define DINNER 256
#define CCONV  16
#define NEIGH  27
#define DSEQ   432   // CCONV * NEIGH
#define DTRANK 14
#define LVOL   4096  // 16*16*16
#define BATCH  2
#define NTOK   8192  // BATCH * LVOL

typedef __attribute__((ext_vector_type(8))) unsigned short ushort8_t;

__device__ __forceinline__ float bf2f(unsigned short u) {
    union { unsigned int i; float f; } v; v.i = ((unsigned int)u) << 16; return v.f;
}
__device__ __forceinline__ unsigned short f2b(float f) {
    __hip_bfloat16 hb = __float2bfloat16(f);
    return *(unsigned short*)&hb;
}

// ---------------------------------------------------------------- merged weight prep
__global__ void k_wprep(const float* __restrict__ w_in, const float* __restrict__ w_fold,
                        const float* __restrict__ w_out, float2* __restrict__ wint2,
                        float* __restrict__ wft2, float* __restrict__ wot2) {
    int idx = blockIdx.x * 256 + threadIdx.x;
    if (idx < 32768) {
        int j = idx >> 8, t = idx & 255;
        wint2[idx] = make_float2(w_in[t * 128 + j], w_in[(t + 256) * 128 + j]);
    } else if (idx < 32768 + 110592) {
        int local = idx - 32768;
        int t = local / 432, d = local - t * 432;
        wft2[(d >> 1) * 512 + t * 2 + (d & 1)] = w_fold[t * 432 + d];
    } else if (idx < 32768 + 110592 + 32768) {
        int local = idx - 32768 - 110592;
        int o = local >> 8, i = local & 255;
        wot2[(i >> 1) * 256 + o * 2 + (i & 1)] = w_out[o * 256 + i];
    }
}

// ---------------------------------------------------------------- in-proj GEMM
__global__ void k_inproj(const float* __restrict__ x, const float2* __restrict__ wint2,
                         float* __restrict__ xpt, float* __restrict__ zbuf) {
    int t = threadIdx.x;
    int tokbase = blockIdx.x * 16;
    int b = tokbase >> 12, lb = tokbase & 4095;
    __shared__ float xs_[16][128];
    for (int idx = t; idx < 2048; idx += 256)
        xs_[idx >> 7][idx & 127] = x[tokbase * 128 + idx];
    __syncthreads();
    float a0[16], a1[16];
#pragma unroll
    for (int k = 0; k < 16; k++) { a0[k] = 0.f; a1[k] = 0.f; }
    for (int j = 0; j < 128; j += 4) {
        float2 w0 = wint2[(j + 0) * 256 + t];
        float2 w1 = wint2[(j + 1) * 256 + t];
        float2 w2 = wint2[(j + 2) * 256 + t];
        float2 w3 = wint2[(j + 3) * 256 + t];
#pragma unroll
        for (int k = 0; k < 16; k++) {
            float4 xv = *(const float4*)&xs_[k][j];
            a0[k] += xv.x * w0.x + xv.y * w1.x + xv.z * w2.x + xv.w * w3.x;
            a1[k] += xv.x * w0.y + xv.y * w1.y + xv.z * w2.y + xv.w * w3.y;
        }
    }
    float* xr = xpt + (size_t)(b * 256 + t) * 4096 + lb;
#pragma unroll
    for (int k = 0; k < 16; k++) xr[k] = a0[k];
#pragma unroll
    for (int k = 0; k < 16; k++) zbuf[(tokbase + k) * 256 + t] = a1[k];
}

// ---------------------------------------------------------------- grouped conv3d + SiLU
__global__ void k_conv(const float* __restrict__ xpt, const float* __restrict__ conv_w,
                       const float* __restrict__ conv_b, float* __restrict__ xc) {
    int t = threadIdx.x;
    int tok = blockIdx.x * 256 + t;
    int co = blockIdx.y;
    int b = tok >> 12, l = tok & 4095;
    int d0 = l >> 8, h0 = (l >> 4) & 15, w0 = l & 15;
    __shared__ float wl[432];
    for (int i = t; i < 432; i += 256) wl[i] = conv_w[co * 432 + i];  // [q][27]
    __syncthreads();
    int nbo[27];
#pragma unroll
    for (int t27 = 0; t27 < 27; t27++) {
        int di = t27 / 9 - 1, dj = (t27 / 3) % 3 - 1, dk = t27 % 3 - 1;
        int zd = d0 + di, zh = h0 + dj, zw = w0 + dk;
        nbo[t27] = ((unsigned)zd > 15u || (unsigned)zh > 15u || (unsigned)zw > 15u)
                   ? -1 : ((zd << 8) + (zh << 4) + zw);
    }
    const float* xb = xpt + (size_t)(b * 256 + co * 16) * 4096;
    float acc0 = conv_b[co], acc1 = 0.f;
    for (int t27 = 0; t27 < 27; t27++) {
        int o = nbo[t27];
        if (o >= 0) {
#pragma unroll
            for (int q = 0; q < 16; q += 2) {
                acc0 += xb[q * 4096 + o]       * wl[q * 27 + t27];
                acc1 += xb[(q + 1) * 4096 + o] * wl[(q + 1) * 27 + t27];
            }
        }
    }
    float acc = acc0 + acc1;
    acc = acc / (1.f + __expf(-acc));  // SiLU
    xc[(b * 16 + co) * 4096 + l] = acc;
}

// ---------------------------------------------------------------- x_dbl = x_proj_w @ unfold(xc)
// TWO channels per block (c, c+23): gather shared, two LDS weight rows.
__global__ void k_xdbl(const float* __restrict__ xc, const float* __restrict__ x_proj_w,
                       float* __restrict__ dts, __hip_bfloat16* __restrict__ bc2) {
    int t = threadIdx.x;
    int tok = blockIdx.x * 256 + t;
    int c0 = blockIdx.y;          // 0..22
    int c1 = c0 + 23;             // 23..45
    int b = tok >> 12, l = tok & 4095;
    int d0 = l >> 8, h0 = (l >> 4) & 15, w0 = l & 15;
    __shared__ float wl0[432], wl1[432];
    for (int i = t; i < 432; i += 256) {
        wl0[i] = x_proj_w[c0 * 432 + i];
        wl1[i] = x_proj_w[c1 * 432 + i];
    }
    __syncthreads();
    int nbo[27];
#pragma unroll
    for (int t27 = 0; t27 < 27; t27++) {
        int di = t27 / 9 - 1, dj = (t27 / 3) % 3 - 1, dk = t27 % 3 - 1;
        int zd = d0 + di, zh = h0 + dj, zw = w0 + dk;
        nbo[t27] = ((unsigned)zd > 15u || (unsigned)zh > 15u || (unsigned)zw > 15u)
                   ? -1 : ((zd << 8) + (zh << 4) + zw);
    }
    const float* xcb = xc + b * 16 * 4096;
    float a00 = 0.f, a01 = 0.f, a10 = 0.f, a11 = 0.f;
    for (int t27 = 0; t27 < 27; t27++) {
        int o = nbo[t27];
        if (o >= 0) {
#pragma unroll
            for (int ch = 0; ch < 16; ch += 2) {
                float v0 = xcb[ch * 4096 + o];
                float v1 = xcb[(ch + 1) * 4096 + o];
                int i0 = ch * 27 + t27, i1 = (ch + 1) * 27 + t27;
                a00 += v0 * wl0[i0];
                a01 += v1 * wl0[i1];
                a10 += v0 * wl1[i0];
                a11 += v1 * wl1[i1];
            }
        }
    }
    float acc0 = a00 + a01;
    float acc1 = a10 + a11;
    if (c0 < 14)
        dts[(size_t)(b * 14 + c0) * 4096 + l] = acc0;
    else
        bc2[(size_t)(b * 32 + (c0 - 14)) * 4096 + l] = __float2bfloat16(acc0);
    bc2[(size_t)(b * 32 + (c1 - 14)) * 4096 + l] = __float2bfloat16(acc1);
}

// ---------------------------------------------------------------- selective scan (+ fused delta)
// Monoid (sdt, Bp[16]) fast path, 17 shuffled values/step; exact fallback.
// y stored bf16 (single 16B store).
__global__ __launch_bounds__(512, 2) void k_scan(
        const float* __restrict__ xc, const float* __restrict__ dts,
        const unsigned short* __restrict__ bc2, const float* __restrict__ dt_w,
        const float* __restrict__ dt_b, const float* __restrict__ A_logs,
        const float* __restrict__ Ds, unsigned short* __restrict__ y) {
    int bd = blockIdx.x;
    int b = bd / 432, dch = bd % 432;
    int t = threadIdx.x;               // 0..511
    int lane = t & 63, wv = t >> 6;    // 8 waves

    bool intA = true;
#pragma unroll
    for (int n = 0; n < 16; n++) {
        float An = -__expf(A_logs[dch * 16 + n]);
        intA = intA && (fabsf(An + (float)(n + 1)) < 1e-3f);
    }
    float Dskip = Ds[dch];

    int cch = dch / 27, t27 = dch % 27;
    int di = t27 / 9 - 1, dj = (t27 / 3) % 3 - 1, dk = t27 % 3 - 1;

    // ---- fused delta: softplus(sum_r dts[b][r][l]*dt_w[dch][r] + dt_b[dch])
    float dtv[8];
    {
        float s[8];
        float bias = dt_b[dch];
#pragma unroll
        for (int i = 0; i < 8; i++) s[i] = bias;
        const float* dsb = dts + (size_t)(b * 14) * 4096 + t * 8;
#pragma unroll
        for (int r = 0; r < 14; r++) {
            float d8[8];
            *(float4*)&d8[0] = *(const float4*)(dsb + (size_t)r * 4096);
            *(float4*)&d8[4] = *(const float4*)(dsb + (size_t)r * 4096 + 4);
            float w = dt_w[dch * 14 + r];
#pragma unroll
            for (int i = 0; i < 8; i++) s[i] += d8[i] * w;
        }
#pragma unroll
        for (int i = 0; i < 8; i++)
            dtv[i] = (s[i] > 15.f) ? s[i] : log1pf(__expf(s[i]));
    }

    // ---- u gather; ys pre-init with Dskip*u
    int d0 = t >> 5, h0 = (t >> 1) & 15, w0 = (t & 1) << 3;
    int zd = d0 + di, zh = h0 + dj;
    bool rowok = ((unsigned)zd <= 15u) && ((unsigned)zh <= 15u);
    const float* xr = xc + (size_t)(b * 16 + cch) * 4096 + (zd << 8) + (zh << 4);
    float dtu[8], ys[8];
#pragma unroll
    for (int i = 0; i < 8; i++) {
        int zw = w0 + i + dk;
        float u = (rowok && (unsigned)zw <= 15u) ? xr[zw] : 0.f;
        dtu[i] = dtv[i] * u;
        ys[i] = Dskip * u;
    }

    const unsigned short* bcb = bc2 + (size_t)(b * 32) * 4096 + t * 8;

    __shared__ float waggA[8][16], waggB[8][16];
    __shared__ float waggS[8];

    float h[16];
    float av[8];

    if (intA) {
        // ======================= FAST PATH =======================
        float aw[8];
#pragma unroll
        for (int i = 0; i < 8; i++) { av[i] = __expf(-dtv[i]); aw[i] = av[i]; }
        float sdt = ((dtv[0] + dtv[1]) + (dtv[2] + dtv[3]))
                  + ((dtv[4] + dtv[5]) + (dtv[6] + dtv[7]));

        // pass 1: Bp only (no Ap array); B prefetched 1-deep
        float Bp[16];
        {
            ushort8_t Bnx = *(const ushort8_t*)(bcb);
#pragma unroll
            for (int n = 0; n < 16; n++) {
                ushort8_t Bv = Bnx;
                if (n < 15) Bnx = *(const ushort8_t*)(bcb + (size_t)(n + 1) * 4096);
                float bp = 0.f;
#pragma unroll
                for (int i = 0; i < 8; i++)
                    bp = aw[i] * bp + dtu[i] * bf2f(Bv[i]);
                Bp[n] = bp;
                if (n < 15) {
#pragma unroll
                    for (int i = 0; i < 8; i++) aw[i] *= av[i];
                }
            }
        }

        // wave-level inclusive scan over (sdt, Bp[16])
#pragma unroll
        for (int s = 1; s < 64; s <<= 1) {
            float psdt = __shfl_up(sdt, s, 64);
            float pl = __expf(-sdt);   // later-segment decay base (before update)
            float pb[16];
#pragma unroll
            for (int n = 0; n < 16; n++) pb[n] = __shfl_up(Bp[n], s, 64);
            if (lane >= s) {
                float pw = pl;
#pragma unroll
                for (int n = 0; n < 16; n++) {
                    Bp[n] = pw * pb[n] + Bp[n];
                    pw *= pl;
                }
                sdt += psdt;
            }
        }

        // cross-wave prefix via tiny LDS
        if (lane == 63) {
            waggS[wv] = sdt;
#pragma unroll
            for (int n = 0; n < 16; n++) waggB[wv][n] = Bp[n];
        }
        __syncthreads();

        float exsdt = __shfl_up(sdt, 1, 64);
        float exB[16];
#pragma unroll
        for (int n = 0; n < 16; n++) exB[n] = __shfl_up(Bp[n], 1, 64);
        if (lane == 0) {
            exsdt = 0.f;
#pragma unroll
            for (int n = 0; n < 16; n++) exB[n] = 0.f;
        }
        float WB[16];
#pragma unroll
        for (int n = 0; n < 16; n++) WB[n] = 0.f;
        for (int ww = 0; ww < wv; ww++) {
            float plw = __expf(-waggS[ww]);
            float pww = plw;
#pragma unroll
            for (int n = 0; n < 16; n++) {
                WB[n] = pww * WB[n] + waggB[ww][n];
                pww *= plw;
            }
        }
        float pex = __expf(-exsdt);
        float pwx = pex;
#pragma unroll
        for (int n = 0; n < 16; n++) {
            h[n] = pwx * WB[n] + exB[n];
            pwx *= pex;
        }
    } else {
        // ======================= FALLBACK (exact) =======================
        float A[16];
#pragma unroll
        for (int n = 0; n < 16; n++) A[n] = -__expf(A_logs[dch * 16 + n]);
        float Ap[16], Bp[16];
        ushort8_t Bnx = *(const ushort8_t*)(bcb);
#pragma unroll
        for (int n = 0; n < 16; n++) {
            ushort8_t Bv = Bnx;
            if (n < 15) Bnx = *(const ushort8_t*)(bcb + (size_t)(n + 1) * 4096);
            float ap = 1.f, bp = 0.f, An = A[n];
#pragma unroll
            for (int i = 0; i < 8; i++) {
                float a = __expf(dtv[i] * An);
                bp = a * bp + dtu[i] * bf2f(Bv[i]);
                ap *= a;
            }
            Ap[n] = ap; Bp[n] = bp;
        }
#pragma unroll
        for (int s = 1; s < 64; s <<= 1) {
#pragma unroll
            for (int n = 0; n < 16; n++) {
                float pa = __shfl_up(Ap[n], s, 64);
                float pb = __shfl_up(Bp[n], s, 64);
                if (lane >= s) {
                    Bp[n] = Ap[n] * pb + Bp[n];
                    Ap[n] *= pa;
                }
            }
        }
        if (lane == 63) {
#pragma unroll
            for (int n = 0; n < 16; n++) { waggA[wv][n] = Ap[n]; waggB[wv][n] = Bp[n]; }
        }
        __syncthreads();
#pragma unroll
        for (int n = 0; n < 16; n++) {
            float exA = __shfl_up(Ap[n], 1, 64);
            float exB = __shfl_up(Bp[n], 1, 64);
            if (lane == 0) { exA = 1.f; exB = 0.f; }
            float WB = 0.f;
            for (int ww = 0; ww < wv; ww++)
                WB = waggA[ww][n] * WB + waggB[ww][n];
            h[n] = exA * WB + exB;
        }
    }

    // ---- pass 2: rescan with incoming state; B,C prefetched 1-deep
    if (intA) {
        float aw[8];
#pragma unroll
        for (int i = 0; i < 8; i++) aw[i] = av[i];
        ushort8_t Bnx = *(const ushort8_t*)(bcb);
        ushort8_t Cnx = *(const ushort8_t*)(bcb + (size_t)16 * 4096);
#pragma unroll
        for (int n = 0; n < 16; n++) {
            ushort8_t Bv = Bnx, Cv = Cnx;
            if (n < 15) {
                Bnx = *(const ushort8_t*)(bcb + (size_t)(n + 1) * 4096);
                Cnx = *(const ushort8_t*)(bcb + (size_t)(17 + n) * 4096);
            }
            float hn = h[n];
#pragma unroll
            for (int i = 0; i < 8; i++) {
                hn = aw[i] * hn + dtu[i] * bf2f(Bv[i]);
                ys[i] += hn * bf2f(Cv[i]);
            }
            if (n < 15) {
#pragma unroll
                for (int i = 0; i < 8; i++) aw[i] *= av[i];
            }
        }
    } else {
        ushort8_t Bnx = *(const ushort8_t*)(bcb);
        ushort8_t Cnx = *(const ushort8_t*)(bcb + (size_t)16 * 4096);
#pragma unroll
        for (int n = 0; n < 16; n++) {
            float An = -__expf(A_logs[dch * 16 + n]);
            ushort8_t Bv = Bnx, Cv = Cnx;
            if (n < 15) {
                Bnx = *(const ushort8_t*)(bcb + (size_t)(n + 1) * 4096);
                Cnx = *(const ushort8_t*)(bcb + (size_t)(17 + n) * 4096);
            }
            float hn = h[n];
#pragma unroll
            for (int i = 0; i < 8; i++) {
                float a = __expf(dtv[i] * An);
                hn = a * hn + dtu[i] * bf2f(Bv[i]);
                ys[i] += hn * bf2f(Cv[i]);
            }
        }
    }

    // ---- store y as bf16 (one 16B store)
    unsigned short* yo = y + (size_t)(b * 432 + dch) * 4096 + t * 8;
    ushort8_t o8;
#pragma unroll
    for (int i = 0; i < 8; i++) o8[i] = f2b(ys[i]);
    *(ushort8_t*)yo = o8;
}

// ---------------------------------------------------------------- fold GEMM + LN + gate + out GEMM
// 128 threads (2 waves), 16 tokens, 2 output cols/thread (t, t+128).
// Float LDS datapath; broadcast-read count per block halves vs R16.
__global__ void k_tail(const unsigned short* __restrict__ y, const float* __restrict__ zbuf,
                       const float2* __restrict__ wft2, const float* __restrict__ ln_g,
                       const float* __restrict__ ln_b, const float2* __restrict__ wot2,
                       float* __restrict__ out) {
    int t = threadIdx.x;              // 0..127
    int tokbase = blockIdx.x * 16;
    int b = tokbase >> 12, lbase = tokbase & 4095;
    __shared__ float ys[432][16];     // 27.6 KB
    __shared__ float vs[256][20];     // 20.5 KB
    __shared__ float mu_s[16], rs_s[16];

    // stage y (bf16 global -> f32 LDS), ushort8-vectorized
    for (int idx = t * 8; idx < 432 * 16; idx += 128 * 8) {
        int d = idx >> 4, tk = idx & 15;
        ushort8_t v = *(const ushort8_t*)(y + (size_t)(b * 432 + d) * 4096 + lbase + tk);
        float f[8];
#pragma unroll
        for (int j = 0; j < 8; j++) f[j] = bf2f(v[j]);
        *(float4*)&ys[d][tk]     = *(float4*)&f[0];
        *(float4*)&ys[d][tk + 4] = *(float4*)&f[4];
    }
    __syncthreads();

    // fold GEMM: 2 d-rows/iter; outputs t and t+128
    float acc0[16], acc1[16];
#pragma unroll
    for (int k = 0; k < 16; k++) { acc0[k] = 0.f; acc1[k] = 0.f; }
    for (int d2 = 0; d2 < 216; d2++) {
        float2 wa = wft2[d2 * 256 + t];
        float2 wb = wft2[d2 * 256 + t + 128];
        const float4* y0 = (const float4*)&ys[2 * d2][0];
        const float4* y1 = (const float4*)&ys[2 * d2 + 1][0];
#pragma unroll
        for (int q = 0; q < 4; q++) {
            float4 a = y0[q], c = y1[q];
            acc0[4 * q + 0] += wa.x * a.x + wa.y * c.x;
            acc0[4 * q + 1] += wa.x * a.y + wa.y * c.y;
            acc0[4 * q + 2] += wa.x * a.z + wa.y * c.z;
            acc0[4 * q + 3] += wa.x * a.w + wa.y * c.w;
            acc1[4 * q + 0] += wb.x * a.x + wb.y * c.x;
            acc1[4 * q + 1] += wb.x * a.y + wb.y * c.y;
            acc1[4 * q + 2] += wb.x * a.z + wb.y * c.z;
            acc1[4 * q + 3] += wb.x * a.w + wb.y * c.w;
        }
    }
#pragma unroll
    for (int q = 0; q < 4; q++) {
        *(float4*)&vs[t][4 * q]       = *(float4*)&acc0[4 * q];
        *(float4*)&vs[t + 128][4 * q] = *(float4*)&acc1[4 * q];
    }
    __syncthreads();

    {   // LN stats: token tk = t>>3, 8 threads/token; rows sub + m*8 (conflict-free)
        int tk = t >> 3, sub = t & 7;
        float s = 0.f, s2 = 0.f;
#pragma unroll
        for (int m = 0; m < 32; m++) {
            float v = vs[sub + m * 8][tk];
            s += v; s2 += v * v;
        }
        s  += __shfl_xor(s, 1, 64);  s2 += __shfl_xor(s2, 1, 64);
        s  += __shfl_xor(s, 2, 64);  s2 += __shfl_xor(s2, 2, 64);
        s  += __shfl_xor(s, 4, 64);  s2 += __shfl_xor(s2, 4, 64);
        if (sub == 0) {
            float mu = s * (1.f / 256.f);
            float var = s2 * (1.f / 256.f) - mu * mu;
            mu_s[tk] = mu;
            rs_s[tk] = rsqrtf(var + 1e-5f);
        }
    }
    __syncthreads();

    float g0 = ln_g[t], b0 = ln_b[t];
    float g1 = ln_g[t + 128], b1 = ln_b[t + 128];
#pragma unroll
    for (int k = 0; k < 16; k++) {
        float z0 = zbuf[(tokbase + k) * 256 + t];
        float z1 = zbuf[(tokbase + k) * 256 + t + 128];
        float s0 = z0 / (1.f + __expf(-z0));
        float s1 = z1 / (1.f + __expf(-z1));
        vs[t][k]       = ((acc0[k] - mu_s[k]) * rs_s[k] * g0 + b0) * s0;
        vs[t + 128][k] = ((acc1[k] - mu_s[k]) * rs_s[k] * g1 + b1) * s1;
    }
    __syncthreads();

    // out GEMM: o = t (0..127), 16 tokens; 2 i-rows/iter
    float oacc[16];
#pragma unroll
    for (int k = 0; k < 16; k++) oacc[k] = 0.f;
    for (int i2 = 0; i2 < 128; i2++) {
        float2 w2 = wot2[i2 * 128 + t];
        const float4* v0 = (const float4*)&vs[2 * i2][0];
        const float4* v1 = (const float4*)&vs[2 * i2 + 1][0];
#pragma unroll
        for (int q = 0; q < 4; q++) {
            float4 a = v0[q], c = v1[q];
            oacc[4 * q + 0] += w2.x * a.x + w2.y * c.x;
            oacc[4 * q + 1] += w2.x * a.y + w2.y * c.y;
            oacc[4 * q + 2] += w2.x * a.z + w2.y * c.z;
            oacc[4 * q + 3] += w2.x * a.w + w2.y * c.w;
        }
    }
#pragma unroll
    for (int k = 0; k < 16; k++)
        out[(tokbase + k) * 128 + t] = oacc[k];
}

// ---------------------------------------------------------------- launch
extern "C" void kernel_launch(void* const* d_in, const int* in_sizes, int n_in,
                              void* d_out, int out_size, void* d_ws, size_t ws_size,
                              hipStream_t stream) {
    const float* x        = (const float*)d_in[0];
    const float* w_in     = (const float*)d_in[1];
    const float* conv_w   = (const float*)d_in[2];
    const float* conv_b   = (const float*)d_in[3];
    const float* x_proj_w = (const float*)d_in[4];
    const float* dt_w     = (const float*)d_in[5];
    const float* dt_b     = (const float*)d_in[6];
    const float* A_logs   = (const float*)d_in[7];
    const float* Ds       = (const float*)d_in[8];
    const float* w_fold   = (const float*)d_in[9];
    const float* ln_g     = (const float*)d_in[10];
    const float* ln_b     = (const float*)d_in[11];
    const float* w_out    = (const float*)d_in[12];
    float* out = (float*)d_out;

    float* ws     = (float*)d_ws;
    float* xpt    = ws;                    // B*256*L       = 2,097,152
    float* zbuf   = xpt    + 2097152;      // NTOK*256      = 2,097,152
    float* xc     = zbuf   + 2097152;      // B*16*L        =   131,072
    float* dts    = xc     + 131072;       // B*14*L        =   114,688
    float* bc2    = dts    + 114688;       // B*32*L bf16   (slot float-sized)
    float* ybuf   = bc2    + 262144;       // B*432*L bf16  (slot float-sized)
    float* wint   = ybuf   + 3538944;      // 128*256 float2 =   65,536
    float* wft    = wint   + 65536;        // 432*256       =   110,592
    float* wot    = wft    + 110592;       // 256*128       =    32,768

    k_wprep<<<dim3(688), dim3(256), 0, stream>>>(w_in, w_fold, w_out,
                                                 (float2*)wint, wft, wot);
    k_inproj<<<dim3(NTOK / 16), dim3(256), 0, stream>>>(x, (const float2*)wint, xpt, zbuf);
    k_conv<<<dim3(NTOK / 256, CCONV), dim3(256), 0, stream>>>(xpt, conv_w, conv_b, xc);
    k_xdbl<<<dim3(NTOK / 256, 23), dim3(256), 0, stream>>>(xc, x_proj_w, dts, (__hip_bfloat16*)bc2);
    k_scan<<<dim3(BATCH * DSEQ), dim3(512), 0, stream>>>(xc, dts, (const unsigned short*)bc2,
                                                         dt_w, dt_b, A_logs, Ds,
                                                         (unsigned short*)ybuf);
    k_tail<<<dim3(NTOK / 16), dim3(128), 0, stream>>>((const unsigned short*)ybuf, zbuf,
                                                      (const float2*)wft, ln_g, ln_b,
                                                      (const float2*)wot, out);
}

// Round 21
// 190.499 us; speedup vs baseline: 1.1413x; 1.1240x over previous
//
#include <hip/hip_runtime.h>
#include <hip/hip_bf16.h>

// Problem constants
#define DM     128
#define DSTATE 16
#define DINNER 256
#define CCONV  16
#define NEIGH  27
#define DSEQ   432   // CCONV * NEIGH
#define DTRANK 14
#define LVOL   4096  // 16*16*16
#define BATCH  2
#define NTOK   8192  // BATCH * LVOL

typedef __attribute__((ext_vector_type(8))) unsigned short ushort8_t;

__device__ __forceinline__ float bf2f(unsigned short u) {
    union { unsigned int i; float f; } v; v.i = ((unsigned int)u) << 16; return v.f;
}

// ---------------------------------------------------------------- merged weight prep
// wint2 (float2): [j][t]; wftT (plain): [d][t] = w_fold[t][d]; wot2: packed pairs.
__global__ void k_wprep(const float* __restrict__ w_in, const float* __restrict__ w_fold,
                        const float* __restrict__ w_out, float2* __restrict__ wint2,
                        float* __restrict__ wftT, float* __restrict__ wot2) {
    int idx = blockIdx.x * 256 + threadIdx.x;
    if (idx < 32768) {
        int j = idx >> 8, t = idx & 255;
        wint2[idx] = make_float2(w_in[t * 128 + j], w_in[(t + 256) * 128 + j]);
    } else if (idx < 32768 + 110592) {
        int local = idx - 32768;
        int t = local / 432, d = local - t * 432;
        wftT[d * 256 + t] = w_fold[local];
    } else if (idx < 32768 + 110592 + 32768) {
        int local = idx - 32768 - 110592;
        int o = local >> 8, i = local & 255;
        wot2[(i >> 1) * 256 + o * 2 + (i & 1)] = w_out[o * 256 + i];
    }
}

// ---------------------------------------------------------------- in-proj GEMM
__global__ void k_inproj(const float* __restrict__ x, const float2* __restrict__ wint2,
                         float* __restrict__ xpt, float* __restrict__ zbuf) {
    int t = threadIdx.x;
    int tokbase = blockIdx.x * 16;
    int b = tokbase >> 12, lb = tokbase & 4095;
    __shared__ float xs_[16][128];
    for (int idx = t; idx < 2048; idx += 256)
        xs_[idx >> 7][idx & 127] = x[tokbase * 128 + idx];
    __syncthreads();
    float a0[16], a1[16];
#pragma unroll
    for (int k = 0; k < 16; k++) { a0[k] = 0.f; a1[k] = 0.f; }
    for (int j = 0; j < 128; j += 4) {
        float2 w0 = wint2[(j + 0) * 256 + t];
        float2 w1 = wint2[(j + 1) * 256 + t];
        float2 w2 = wint2[(j + 2) * 256 + t];
        float2 w3 = wint2[(j + 3) * 256 + t];
#pragma unroll
        for (int k = 0; k < 16; k++) {
            float4 xv = *(const float4*)&xs_[k][j];
            a0[k] += xv.x * w0.x + xv.y * w1.x + xv.z * w2.x + xv.w * w3.x;
            a1[k] += xv.x * w0.y + xv.y * w1.y + xv.z * w2.y + xv.w * w3.y;
        }
    }
    float* xr = xpt + (size_t)(b * 256 + t) * 4096 + lb;
#pragma unroll
    for (int k = 0; k < 16; k++) xr[k] = a0[k];
#pragma unroll
    for (int k = 0; k < 16; k++) zbuf[(tokbase + k) * 256 + t] = a1[k];
}

// ---------------------------------------------------------------- grouped conv3d + SiLU
__global__ void k_conv(const float* __restrict__ xpt, const float* __restrict__ conv_w,
                       const float* __restrict__ conv_b, float* __restrict__ xc) {
    int t = threadIdx.x;
    int tok = blockIdx.x * 256 + t;
    int co = blockIdx.y;
    int b = tok >> 12, l = tok & 4095;
    int d0 = l >> 8, h0 = (l >> 4) & 15, w0 = l & 15;
    __shared__ float wl[432];
    for (int i = t; i < 432; i += 256) wl[i] = conv_w[co * 432 + i];  // [q][27]
    __syncthreads();
    int nbo[27];
#pragma unroll
    for (int t27 = 0; t27 < 27; t27++) {
        int di = t27 / 9 - 1, dj = (t27 / 3) % 3 - 1, dk = t27 % 3 - 1;
        int zd = d0 + di, zh = h0 + dj, zw = w0 + dk;
        nbo[t27] = ((unsigned)zd > 15u || (unsigned)zh > 15u || (unsigned)zw > 15u)
                   ? -1 : ((zd << 8) + (zh << 4) + zw);
    }
    const float* xb = xpt + (size_t)(b * 256 + co * 16) * 4096;
    float acc0 = conv_b[co], acc1 = 0.f;
    for (int t27 = 0; t27 < 27; t27++) {
        int o = nbo[t27];
        if (o >= 0) {
#pragma unroll
            for (int q = 0; q < 16; q += 2) {
                acc0 += xb[q * 4096 + o]       * wl[q * 27 + t27];
                acc1 += xb[(q + 1) * 4096 + o] * wl[(q + 1) * 27 + t27];
            }
        }
    }
    float acc = acc0 + acc1;
    acc = acc / (1.f + __expf(-acc));  // SiLU
    xc[(b * 16 + co) * 4096 + l] = acc;
}

// ---------------------------------------------------------------- x_dbl = x_proj_w @ unfold(xc)
// TWO channels per block (c, c+23): gather shared, two LDS weight rows.
__global__ void k_xdbl(const float* __restrict__ xc, const float* __restrict__ x_proj_w,
                       float* __restrict__ dts, __hip_bfloat16* __restrict__ bc2) {
    int t = threadIdx.x;
    int tok = blockIdx.x * 256 + t;
    int c0 = blockIdx.y;          // 0..22
    int c1 = c0 + 23;             // 23..45
    int b = tok >> 12, l = tok & 4095;
    int d0 = l >> 8, h0 = (l >> 4) & 15, w0 = l & 15;
    __shared__ float wl0[432], wl1[432];
    for (int i = t; i < 432; i += 256) {
        wl0[i] = x_proj_w[c0 * 432 + i];
        wl1[i] = x_proj_w[c1 * 432 + i];
    }
    __syncthreads();
    int nbo[27];
#pragma unroll
    for (int t27 = 0; t27 < 27; t27++) {
        int di = t27 / 9 - 1, dj = (t27 / 3) % 3 - 1, dk = t27 % 3 - 1;
        int zd = d0 + di, zh = h0 + dj, zw = w0 + dk;
        nbo[t27] = ((unsigned)zd > 15u || (unsigned)zh > 15u || (unsigned)zw > 15u)
                   ? -1 : ((zd << 8) + (zh << 4) + zw);
    }
    const float* xcb = xc + b * 16 * 4096;
    float a00 = 0.f, a01 = 0.f, a10 = 0.f, a11 = 0.f;
    for (int t27 = 0; t27 < 27; t27++) {
        int o = nbo[t27];
        if (o >= 0) {
#pragma unroll
            for (int ch = 0; ch < 16; ch += 2) {
                float v0 = xcb[ch * 4096 + o];
                float v1 = xcb[(ch + 1) * 4096 + o];
                int i0 = ch * 27 + t27, i1 = (ch + 1) * 27 + t27;
                a00 += v0 * wl0[i0];
                a01 += v1 * wl0[i1];
                a10 += v0 * wl1[i0];
                a11 += v1 * wl1[i1];
            }
        }
    }
    float acc0 = a00 + a01;
    float acc1 = a10 + a11;
    if (c0 < 14)
        dts[(size_t)(b * 14 + c0) * 4096 + l] = acc0;
    else
        bc2[(size_t)(b * 32 + (c0 - 14)) * 4096 + l] = __float2bfloat16(acc0);
    bc2[(size_t)(b * 32 + (c1 - 14)) * 4096 + l] = __float2bfloat16(acc1);
}

// ---------------------------------------------------------------- selective scan (+ fused delta)
// R16 exact kernel: monoid (sdt, Bp[16]) fast path, f32 y output.
__global__ __launch_bounds__(512, 2) void k_scan(
        const float* __restrict__ xc, const float* __restrict__ dts,
        const unsigned short* __restrict__ bc2, const float* __restrict__ dt_w,
        const float* __restrict__ dt_b, const float* __restrict__ A_logs,
        const float* __restrict__ Ds, float* __restrict__ y) {
    int bd = blockIdx.x;
    int b = bd / 432, dch = bd % 432;
    int t = threadIdx.x;               // 0..511
    int lane = t & 63, wv = t >> 6;    // 8 waves

    bool intA = true;
#pragma unroll
    for (int n = 0; n < 16; n++) {
        float An = -__expf(A_logs[dch * 16 + n]);
        intA = intA && (fabsf(An + (float)(n + 1)) < 1e-3f);
    }
    float Dskip = Ds[dch];

    int cch = dch / 27, t27 = dch % 27;
    int di = t27 / 9 - 1, dj = (t27 / 3) % 3 - 1, dk = t27 % 3 - 1;

    // ---- fused delta: softplus(sum_r dts[b][r][l]*dt_w[dch][r] + dt_b[dch])
    float dtv[8];
    {
        float s[8];
        float bias = dt_b[dch];
#pragma unroll
        for (int i = 0; i < 8; i++) s[i] = bias;
        const float* dsb = dts + (size_t)(b * 14) * 4096 + t * 8;
#pragma unroll
        for (int r = 0; r < 14; r++) {
            float d8[8];
            *(float4*)&d8[0] = *(const float4*)(dsb + (size_t)r * 4096);
            *(float4*)&d8[4] = *(const float4*)(dsb + (size_t)r * 4096 + 4);
            float w = dt_w[dch * 14 + r];
#pragma unroll
            for (int i = 0; i < 8; i++) s[i] += d8[i] * w;
        }
#pragma unroll
        for (int i = 0; i < 8; i++)
            dtv[i] = (s[i] > 15.f) ? s[i] : log1pf(__expf(s[i]));
    }

    // ---- u gather; ys pre-init with Dskip*u
    int d0 = t >> 5, h0 = (t >> 1) & 15, w0 = (t & 1) << 3;
    int zd = d0 + di, zh = h0 + dj;
    bool rowok = ((unsigned)zd <= 15u) && ((unsigned)zh <= 15u);
    const float* xr = xc + (size_t)(b * 16 + cch) * 4096 + (zd << 8) + (zh << 4);
    float dtu[8], ys[8];
#pragma unroll
    for (int i = 0; i < 8; i++) {
        int zw = w0 + i + dk;
        float u = (rowok && (unsigned)zw <= 15u) ? xr[zw] : 0.f;
        dtu[i] = dtv[i] * u;
        ys[i] = Dskip * u;
    }

    const unsigned short* bcb = bc2 + (size_t)(b * 32) * 4096 + t * 8;

    __shared__ float waggA[8][16], waggB[8][16];
    __shared__ float waggS[8];

    float h[16];
    float av[8];

    if (intA) {
        // ======================= FAST PATH =======================
        float aw[8];
#pragma unroll
        for (int i = 0; i < 8; i++) { av[i] = __expf(-dtv[i]); aw[i] = av[i]; }
        float sdt = ((dtv[0] + dtv[1]) + (dtv[2] + dtv[3]))
                  + ((dtv[4] + dtv[5]) + (dtv[6] + dtv[7]));

        // pass 1: Bp only (no Ap array); B prefetched 1-deep
        float Bp[16];
        {
            ushort8_t Bnx = *(const ushort8_t*)(bcb);
#pragma unroll
            for (int n = 0; n < 16; n++) {
                ushort8_t Bv = Bnx;
                if (n < 15) Bnx = *(const ushort8_t*)(bcb + (size_t)(n + 1) * 4096);
                float bp = 0.f;
#pragma unroll
                for (int i = 0; i < 8; i++)
                    bp = aw[i] * bp + dtu[i] * bf2f(Bv[i]);
                Bp[n] = bp;
                if (n < 15) {
#pragma unroll
                    for (int i = 0; i < 8; i++) aw[i] *= av[i];
                }
            }
        }

        // wave-level inclusive scan over (sdt, Bp[16])
#pragma unroll
        for (int s = 1; s < 64; s <<= 1) {
            float psdt = __shfl_up(sdt, s, 64);
            float pl = __expf(-sdt);   // later-segment decay base (before update)
            float pb[16];
#pragma unroll
            for (int n = 0; n < 16; n++) pb[n] = __shfl_up(Bp[n], s, 64);
            if (lane >= s) {
                float pw = pl;
#pragma unroll
                for (int n = 0; n < 16; n++) {
                    Bp[n] = pw * pb[n] + Bp[n];
                    pw *= pl;
                }
                sdt += psdt;
            }
        }

        // cross-wave prefix via tiny LDS
        if (lane == 63) {
            waggS[wv] = sdt;
#pragma unroll
            for (int n = 0; n < 16; n++) waggB[wv][n] = Bp[n];
        }
        __syncthreads();

        float exsdt = __shfl_up(sdt, 1, 64);
        float exB[16];
#pragma unroll
        for (int n = 0; n < 16; n++) exB[n] = __shfl_up(Bp[n], 1, 64);
        if (lane == 0) {
            exsdt = 0.f;
#pragma unroll
            for (int n = 0; n < 16; n++) exB[n] = 0.f;
        }
        float WB[16];
#pragma unroll
        for (int n = 0; n < 16; n++) WB[n] = 0.f;
        for (int ww = 0; ww < wv; ww++) {
            float plw = __expf(-waggS[ww]);
            float pww = plw;
#pragma unroll
            for (int n = 0; n < 16; n++) {
                WB[n] = pww * WB[n] + waggB[ww][n];
                pww *= plw;
            }
        }
        float pex = __expf(-exsdt);
        float pwx = pex;
#pragma unroll
        for (int n = 0; n < 16; n++) {
            h[n] = pwx * WB[n] + exB[n];
            pwx *= pex;
        }
    } else {
        // ======================= FALLBACK (exact) =======================
        float A[16];
#pragma unroll
        for (int n = 0; n < 16; n++) A[n] = -__expf(A_logs[dch * 16 + n]);
        float Ap[16], Bp[16];
        ushort8_t Bnx = *(const ushort8_t*)(bcb);
#pragma unroll
        for (int n = 0; n < 16; n++) {
            ushort8_t Bv = Bnx;
            if (n < 15) Bnx = *(const ushort8_t*)(bcb + (size_t)(n + 1) * 4096);
            float ap = 1.f, bp = 0.f, An = A[n];
#pragma unroll
            for (int i = 0; i < 8; i++) {
                float a = __expf(dtv[i] * An);
                bp = a * bp + dtu[i] * bf2f(Bv[i]);
                ap *= a;
            }
            Ap[n] = ap; Bp[n] = bp;
        }
#pragma unroll
        for (int s = 1; s < 64; s <<= 1) {
#pragma unroll
            for (int n = 0; n < 16; n++) {
                float pa = __shfl_up(Ap[n], s, 64);
                float pb = __shfl_up(Bp[n], s, 64);
                if (lane >= s) {
                    Bp[n] = Ap[n] * pb + Bp[n];
                    Ap[n] *= pa;
                }
            }
        }
        if (lane == 63) {
#pragma unroll
            for (int n = 0; n < 16; n++) { waggA[wv][n] = Ap[n]; waggB[wv][n] = Bp[n]; }
        }
        __syncthreads();
#pragma unroll
        for (int n = 0; n < 16; n++) {
            float exA = __shfl_up(Ap[n], 1, 64);
            float exB = __shfl_up(Bp[n], 1, 64);
            if (lane == 0) { exA = 1.f; exB = 0.f; }
            float WB = 0.f;
            for (int ww = 0; ww < wv; ww++)
                WB = waggA[ww][n] * WB + waggB[ww][n];
            h[n] = exA * WB + exB;
        }
    }

    // ---- pass 2: rescan with incoming state; B,C prefetched 1-deep
    if (intA) {
        float aw[8];
#pragma unroll
        for (int i = 0; i < 8; i++) aw[i] = av[i];
        ushort8_t Bnx = *(const ushort8_t*)(bcb);
        ushort8_t Cnx = *(const ushort8_t*)(bcb + (size_t)16 * 4096);
#pragma unroll
        for (int n = 0; n < 16; n++) {
            ushort8_t Bv = Bnx, Cv = Cnx;
            if (n < 15) {
                Bnx = *(const ushort8_t*)(bcb + (size_t)(n + 1) * 4096);
                Cnx = *(const ushort8_t*)(bcb + (size_t)(17 + n) * 4096);
            }
            float hn = h[n];
#pragma unroll
            for (int i = 0; i < 8; i++) {
                hn = aw[i] * hn + dtu[i] * bf2f(Bv[i]);
                ys[i] += hn * bf2f(Cv[i]);
            }
            if (n < 15) {
#pragma unroll
                for (int i = 0; i < 8; i++) aw[i] *= av[i];
            }
        }
    } else {
        ushort8_t Bnx = *(const ushort8_t*)(bcb);
        ushort8_t Cnx = *(const ushort8_t*)(bcb + (size_t)16 * 4096);
#pragma unroll
        for (int n = 0; n < 16; n++) {
            float An = -__expf(A_logs[dch * 16 + n]);
            ushort8_t Bv = Bnx, Cv = Cnx;
            if (n < 15) {
                Bnx = *(const ushort8_t*)(bcb + (size_t)(n + 1) * 4096);
                Cnx = *(const ushort8_t*)(bcb + (size_t)(17 + n) * 4096);
            }
            float hn = h[n];
#pragma unroll
            for (int i = 0; i < 8; i++) {
                float a = __expf(dtv[i] * An);
                hn = a * hn + dtu[i] * bf2f(Bv[i]);
                ys[i] += hn * bf2f(Cv[i]);
            }
        }
    }

    float* yo = y + (size_t)(b * 432 + dch) * 4096 + t * 8;
    *(float4*)(yo)     = *(float4*)&ys[0];
    *(float4*)(yo + 4) = *(float4*)&ys[4];
}

// ---------------------------------------------------------------- fold GEMM + LN + gate + out GEMM
// Fold reads y DIRECTLY FROM GLOBAL with wave-uniform addresses -> compiler
// scalarizes to s_load (scalar cache pipe), eliminating the 1728 b128 LDS
// broadcasts/wave that bounded R16-R18. Out GEMM keeps LDS vs (512 b128/wave).
__global__ void k_tail(const float* __restrict__ y, const float* __restrict__ zbuf,
                       const float* __restrict__ wftT, const float* __restrict__ ln_g,
                       const float* __restrict__ ln_b, const float2* __restrict__ wot2,
                       float* __restrict__ out) {
    int t = threadIdx.x;
    int tokbase = blockIdx.x * 16;
    int b = tokbase >> 12, lbase = tokbase & 4095;
    __shared__ float vs[256][20];
    __shared__ float mu_s[16], rs_s[16];

    const float* yb = y + (size_t)b * 432 * 4096 + lbase;   // uniform base

    // fold GEMM: weights coalesced per-thread, y rows via uniform scalar loads
    float acc[16];
#pragma unroll
    for (int k = 0; k < 16; k++) acc[k] = 0.f;
    for (int d = 0; d < 432; d += 2) {
        float w0 = wftT[d * 256 + t];
        float w1 = wftT[(d + 1) * 256 + t];
        const float* yr0 = yb + (size_t)d * 4096;
        const float* yr1 = yr0 + 4096;
#pragma unroll
        for (int k = 0; k < 16; k++)
            acc[k] += w0 * yr0[k] + w1 * yr1[k];
    }
#pragma unroll
    for (int q = 0; q < 4; q++)
        *(float4*)&vs[t][4 * q] = *(float4*)&acc[4 * q];
    __syncthreads();

    {   // LN stats: token tk = t>>4, 16 threads/token; rows sub + m*16
        int tk = t >> 4, sub = t & 15;
        float s = 0.f, s2 = 0.f;
#pragma unroll
        for (int m = 0; m < 16; m++) {
            float v = vs[sub + m * 16][tk];
            s += v; s2 += v * v;
        }
        s  += __shfl_xor(s, 1, 64);  s2 += __shfl_xor(s2, 1, 64);
        s  += __shfl_xor(s, 2, 64);  s2 += __shfl_xor(s2, 2, 64);
        s  += __shfl_xor(s, 4, 64);  s2 += __shfl_xor(s2, 4, 64);
        s  += __shfl_xor(s, 8, 64);  s2 += __shfl_xor(s2, 8, 64);
        if (sub == 0) {
            float mu = s * (1.f / 256.f);
            float var = s2 * (1.f / 256.f) - mu * mu;
            mu_s[tk] = mu;
            rs_s[tk] = rsqrtf(var + 1e-5f);
        }
    }
    __syncthreads();

    float g = ln_g[t], be = ln_b[t];
#pragma unroll
    for (int k = 0; k < 16; k++) {
        float zv = zbuf[(tokbase + k) * 256 + t];
        float sz = zv / (1.f + __expf(-zv));  // SiLU(z)
        vs[t][k] = ((acc[k] - mu_s[k]) * rs_s[k] * g + be) * sz;
    }
    __syncthreads();

    // out GEMM: 2 i-rows/iter; each thread 1 output x 8 tokens
    float oacc[8];
#pragma unroll
    for (int k = 0; k < 8; k++) oacc[k] = 0.f;
    int o = t & 127, kh = (t >> 7) * 8;
    for (int i2 = 0; i2 < 128; i2++) {
        float2 w2 = wot2[i2 * 128 + o];
        float4 v0 = *(const float4*)&vs[2 * i2][kh];
        float4 v1 = *(const float4*)&vs[2 * i2][kh + 4];
        float4 u0 = *(const float4*)&vs[2 * i2 + 1][kh];
        float4 u1 = *(const float4*)&vs[2 * i2 + 1][kh + 4];
        oacc[0] += w2.x * v0.x + w2.y * u0.x;
        oacc[1] += w2.x * v0.y + w2.y * u0.y;
        oacc[2] += w2.x * v0.z + w2.y * u0.z;
        oacc[3] += w2.x * v0.w + w2.y * u0.w;
        oacc[4] += w2.x * v1.x + w2.y * u1.x;
        oacc[5] += w2.x * v1.y + w2.y * u1.y;
        oacc[6] += w2.x * v1.z + w2.y * u1.z;
        oacc[7] += w2.x * v1.w + w2.y * u1.w;
    }
#pragma unroll
    for (int k = 0; k < 8; k++)
        out[(tokbase + kh + k) * 128 + o] = oacc[k];
}

// ---------------------------------------------------------------- launch
extern "C" void kernel_launch(void* const* d_in, const int* in_sizes, int n_in,
                              void* d_out, int out_size, void* d_ws, size_t ws_size,
                              hipStream_t stream) {
    const float* x        = (const float*)d_in[0];
    const float* w_in     = (const float*)d_in[1];
    const float* conv_w   = (const float*)d_in[2];
    const float* conv_b   = (const float*)d_in[3];
    const float* x_proj_w = (const float*)d_in[4];
    const float* dt_w     = (const float*)d_in[5];
    const float* dt_b     = (const float*)d_in[6];
    const float* A_logs   = (const float*)d_in[7];
    const float* Ds       = (const float*)d_in[8];
    const float* w_fold   = (const float*)d_in[9];
    const float* ln_g     = (const float*)d_in[10];
    const float* ln_b     = (const float*)d_in[11];
    const float* w_out    = (const float*)d_in[12];
    float* out = (float*)d_out;

    float* ws     = (float*)d_ws;
    float* xpt    = ws;                    // B*256*L       = 2,097,152
    float* zbuf   = xpt    + 2097152;      // NTOK*256      = 2,097,152
    float* xc     = zbuf   + 2097152;      // B*16*L        =   131,072
    float* dts    = xc     + 131072;       // B*14*L        =   114,688
    float* bc2    = dts    + 114688;       // B*32*L bf16   (slot float-sized)
    float* ybuf   = bc2    + 262144;       // B*432*L       = 3,538,944
    float* wint   = ybuf   + 3538944;      // 128*256 float2 =   65,536
    float* wft    = wint   + 65536;        // 432*256       =   110,592
    float* wot    = wft    + 110592;       // 256*128       =    32,768

    k_wprep<<<dim3(688), dim3(256), 0, stream>>>(w_in, w_fold, w_out,
                                                 (float2*)wint, wft, wot);
    k_inproj<<<dim3(NTOK / 16), dim3(256), 0, stream>>>(x, (const float2*)wint, xpt, zbuf);
    k_conv<<<dim3(NTOK / 256, CCONV), dim3(256), 0, stream>>>(xpt, conv_w, conv_b, xc);
    k_xdbl<<<dim3(NTOK / 256, 23), dim3(256), 0, stream>>>(xc, x_proj_w, dts, (__hip_bfloat16*)bc2);
    k_scan<<<dim3(BATCH * DSEQ), dim3(512), 0, stream>>>(xc, dts, (const unsigned short*)bc2,
                                                         dt_w, dt_b, A_logs, Ds, ybuf);
    k_tail<<<dim3(NTOK / 16), dim3(256), 0, stream>>>(ybuf, zbuf, wft, ln_g, ln_b,
                                                      (const float2*)wot, out);
}

// Round 22
// 147.871 us; speedup vs baseline: 1.4703x; 1.2883x over previous
//
#include <hip/hip_runtime.h>
#include <hip/hip_bf16.h>

// Problem constants
#define DM     128
#define DSTATE 16
#define DINNER 256
#define CCONV  16
#define NEIGH  27
#define DSEQ   432   // CCONV * NEIGH
#define DTRANK 14
#define LVOL   4096  // 16*16*16
#define BATCH  2
#define NTOK   8192  // BATCH * LVOL

typedef __attribute__((ext_vector_type(8))) unsigned short ushort8_t;
typedef __attribute__((ext_vector_type(8))) short short8_t;   // bf16x8 MFMA frag
typedef __attribute__((ext_vector_type(4))) float f32x4_t;    // MFMA acc

__device__ __forceinline__ float bf2f(unsigned short u) {
    union { unsigned int i; float f; } v; v.i = ((unsigned int)u) << 16; return v.f;
}
__device__ __forceinline__ unsigned short f2b(float f) {
    __hip_bfloat16 hb = __float2bfloat16(f);
    return *(unsigned short*)&hb;
}

// ---------------------------------------------------------------- merged weight prep
// wint2 (float2): [j][t]; wfb bf16 [256][448] (d>=432 zero); wob bf16 [128][256]
__global__ void k_wprep(const float* __restrict__ w_in, const float* __restrict__ w_fold,
                        const float* __restrict__ w_out, float2* __restrict__ wint2,
                        unsigned short* __restrict__ wfb, unsigned short* __restrict__ wob) {
    int idx = blockIdx.x * 256 + threadIdx.x;
    if (idx < 32768) {
        int j = idx >> 8, t = idx & 255;
        wint2[idx] = make_float2(w_in[t * 128 + j], w_in[(t + 256) * 128 + j]);
    } else if (idx < 32768 + 114688) {
        int local = idx - 32768;
        int o = local / 448, dk = local - o * 448;
        wfb[local] = (dk < 432) ? f2b(w_fold[o * 432 + dk]) : (unsigned short)0;
    } else if (idx < 32768 + 114688 + 32768) {
        int local = idx - 32768 - 114688;
        wob[local] = f2b(w_out[local]);
    }
}

// ---------------------------------------------------------------- in-proj GEMM
__global__ void k_inproj(const float* __restrict__ x, const float2* __restrict__ wint2,
                         float* __restrict__ xpt, float* __restrict__ zbuf) {
    int t = threadIdx.x;
    int tokbase = blockIdx.x * 16;
    int b = tokbase >> 12, lb = tokbase & 4095;
    __shared__ float xs_[16][128];
    for (int idx = t; idx < 2048; idx += 256)
        xs_[idx >> 7][idx & 127] = x[tokbase * 128 + idx];
    __syncthreads();
    float a0[16], a1[16];
#pragma unroll
    for (int k = 0; k < 16; k++) { a0[k] = 0.f; a1[k] = 0.f; }
    for (int j = 0; j < 128; j += 4) {
        float2 w0 = wint2[(j + 0) * 256 + t];
        float2 w1 = wint2[(j + 1) * 256 + t];
        float2 w2 = wint2[(j + 2) * 256 + t];
        float2 w3 = wint2[(j + 3) * 256 + t];
#pragma unroll
        for (int k = 0; k < 16; k++) {
            float4 xv = *(const float4*)&xs_[k][j];
            a0[k] += xv.x * w0.x + xv.y * w1.x + xv.z * w2.x + xv.w * w3.x;
            a1[k] += xv.x * w0.y + xv.y * w1.y + xv.z * w2.y + xv.w * w3.y;
        }
    }
    float* xr = xpt + (size_t)(b * 256 + t) * 4096 + lb;
#pragma unroll
    for (int k = 0; k < 16; k++) xr[k] = a0[k];
#pragma unroll
    for (int k = 0; k < 16; k++) zbuf[(tokbase + k) * 256 + t] = a1[k];
}

// ---------------------------------------------------------------- grouped conv3d + SiLU
__global__ void k_conv(const float* __restrict__ xpt, const float* __restrict__ conv_w,
                       const float* __restrict__ conv_b, float* __restrict__ xc) {
    int t = threadIdx.x;
    int tok = blockIdx.x * 256 + t;
    int co = blockIdx.y;
    int b = tok >> 12, l = tok & 4095;
    int d0 = l >> 8, h0 = (l >> 4) & 15, w0 = l & 15;
    __shared__ float wl[432];
    for (int i = t; i < 432; i += 256) wl[i] = conv_w[co * 432 + i];  // [q][27]
    __syncthreads();
    int nbo[27];
#pragma unroll
    for (int t27 = 0; t27 < 27; t27++) {
        int di = t27 / 9 - 1, dj = (t27 / 3) % 3 - 1, dk = t27 % 3 - 1;
        int zd = d0 + di, zh = h0 + dj, zw = w0 + dk;
        nbo[t27] = ((unsigned)zd > 15u || (unsigned)zh > 15u || (unsigned)zw > 15u)
                   ? -1 : ((zd << 8) + (zh << 4) + zw);
    }
    const float* xb = xpt + (size_t)(b * 256 + co * 16) * 4096;
    float acc0 = conv_b[co], acc1 = 0.f;
    for (int t27 = 0; t27 < 27; t27++) {
        int o = nbo[t27];
        if (o >= 0) {
#pragma unroll
            for (int q = 0; q < 16; q += 2) {
                acc0 += xb[q * 4096 + o]       * wl[q * 27 + t27];
                acc1 += xb[(q + 1) * 4096 + o] * wl[(q + 1) * 27 + t27];
            }
        }
    }
    float acc = acc0 + acc1;
    acc = acc / (1.f + __expf(-acc));  // SiLU
    xc[(b * 16 + co) * 4096 + l] = acc;
}

// ---------------------------------------------------------------- x_dbl = x_proj_w @ unfold(xc)
// TWO channels per block (c, c+23): gather shared, two LDS weight rows.
__global__ void k_xdbl(const float* __restrict__ xc, const float* __restrict__ x_proj_w,
                       float* __restrict__ dts, __hip_bfloat16* __restrict__ bc2) {
    int t = threadIdx.x;
    int tok = blockIdx.x * 256 + t;
    int c0 = blockIdx.y;          // 0..22
    int c1 = c0 + 23;             // 23..45
    int b = tok >> 12, l = tok & 4095;
    int d0 = l >> 8, h0 = (l >> 4) & 15, w0 = l & 15;
    __shared__ float wl0[432], wl1[432];
    for (int i = t; i < 432; i += 256) {
        wl0[i] = x_proj_w[c0 * 432 + i];
        wl1[i] = x_proj_w[c1 * 432 + i];
    }
    __syncthreads();
    int nbo[27];
#pragma unroll
    for (int t27 = 0; t27 < 27; t27++) {
        int di = t27 / 9 - 1, dj = (t27 / 3) % 3 - 1, dk = t27 % 3 - 1;
        int zd = d0 + di, zh = h0 + dj, zw = w0 + dk;
        nbo[t27] = ((unsigned)zd > 15u || (unsigned)zh > 15u || (unsigned)zw > 15u)
                   ? -1 : ((zd << 8) + (zh << 4) + zw);
    }
    const float* xcb = xc + b * 16 * 4096;
    float a00 = 0.f, a01 = 0.f, a10 = 0.f, a11 = 0.f;
    for (int t27 = 0; t27 < 27; t27++) {
        int o = nbo[t27];
        if (o >= 0) {
#pragma unroll
            for (int ch = 0; ch < 16; ch += 2) {
                float v0 = xcb[ch * 4096 + o];
                float v1 = xcb[(ch + 1) * 4096 + o];
                int i0 = ch * 27 + t27, i1 = (ch + 1) * 27 + t27;
                a00 += v0 * wl0[i0];
                a01 += v1 * wl0[i1];
                a10 += v0 * wl1[i0];
                a11 += v1 * wl1[i1];
            }
        }
    }
    float acc0 = a00 + a01;
    float acc1 = a10 + a11;
    if (c0 < 14)
        dts[(size_t)(b * 14 + c0) * 4096 + l] = acc0;
    else
        bc2[(size_t)(b * 32 + (c0 - 14)) * 4096 + l] = __float2bfloat16(acc0);
    bc2[(size_t)(b * 32 + (c1 - 14)) * 4096 + l] = __float2bfloat16(acc1);
}

// ---------------------------------------------------------------- selective scan (+ fused delta)
// R19's verified kernel: monoid (sdt, Bp[16]) fast path; bf16 y output.
__global__ __launch_bounds__(512, 2) void k_scan(
        const float* __restrict__ xc, const float* __restrict__ dts,
        const unsigned short* __restrict__ bc2, const float* __restrict__ dt_w,
        const float* __restrict__ dt_b, const float* __restrict__ A_logs,
        const float* __restrict__ Ds, unsigned short* __restrict__ y) {
    int bd = blockIdx.x;
    int b = bd / 432, dch = bd % 432;
    int t = threadIdx.x;               // 0..511
    int lane = t & 63, wv = t >> 6;    // 8 waves

    bool intA = true;
#pragma unroll
    for (int n = 0; n < 16; n++) {
        float An = -__expf(A_logs[dch * 16 + n]);
        intA = intA && (fabsf(An + (float)(n + 1)) < 1e-3f);
    }
    float Dskip = Ds[dch];

    int cch = dch / 27, t27 = dch % 27;
    int di = t27 / 9 - 1, dj = (t27 / 3) % 3 - 1, dk = t27 % 3 - 1;

    // ---- fused delta: softplus(sum_r dts[b][r][l]*dt_w[dch][r] + dt_b[dch])
    float dtv[8];
    {
        float s[8];
        float bias = dt_b[dch];
#pragma unroll
        for (int i = 0; i < 8; i++) s[i] = bias;
        const float* dsb = dts + (size_t)(b * 14) * 4096 + t * 8;
#pragma unroll
        for (int r = 0; r < 14; r++) {
            float d8[8];
            *(float4*)&d8[0] = *(const float4*)(dsb + (size_t)r * 4096);
            *(float4*)&d8[4] = *(const float4*)(dsb + (size_t)r * 4096 + 4);
            float w = dt_w[dch * 14 + r];
#pragma unroll
            for (int i = 0; i < 8; i++) s[i] += d8[i] * w;
        }
#pragma unroll
        for (int i = 0; i < 8; i++)
            dtv[i] = (s[i] > 15.f) ? s[i] : log1pf(__expf(s[i]));
    }

    // ---- u gather; ys pre-init with Dskip*u
    int d0 = t >> 5, h0 = (t >> 1) & 15, w0 = (t & 1) << 3;
    int zd = d0 + di, zh = h0 + dj;
    bool rowok = ((unsigned)zd <= 15u) && ((unsigned)zh <= 15u);
    const float* xr = xc + (size_t)(b * 16 + cch) * 4096 + (zd << 8) + (zh << 4);
    float dtu[8], ys[8];
#pragma unroll
    for (int i = 0; i < 8; i++) {
        int zw = w0 + i + dk;
        float u = (rowok && (unsigned)zw <= 15u) ? xr[zw] : 0.f;
        dtu[i] = dtv[i] * u;
        ys[i] = Dskip * u;
    }

    const unsigned short* bcb = bc2 + (size_t)(b * 32) * 4096 + t * 8;

    __shared__ float waggA[8][16], waggB[8][16];
    __shared__ float waggS[8];

    float h[16];
    float av[8];

    if (intA) {
        // ======================= FAST PATH =======================
        float aw[8];
#pragma unroll
        for (int i = 0; i < 8; i++) { av[i] = __expf(-dtv[i]); aw[i] = av[i]; }
        float sdt = ((dtv[0] + dtv[1]) + (dtv[2] + dtv[3]))
                  + ((dtv[4] + dtv[5]) + (dtv[6] + dtv[7]));

        float Bp[16];
        {
            ushort8_t Bnx = *(const ushort8_t*)(bcb);
#pragma unroll
            for (int n = 0; n < 16; n++) {
                ushort8_t Bv = Bnx;
                if (n < 15) Bnx = *(const ushort8_t*)(bcb + (size_t)(n + 1) * 4096);
                float bp = 0.f;
#pragma unroll
                for (int i = 0; i < 8; i++)
                    bp = aw[i] * bp + dtu[i] * bf2f(Bv[i]);
                Bp[n] = bp;
                if (n < 15) {
#pragma unroll
                    for (int i = 0; i < 8; i++) aw[i] *= av[i];
                }
            }
        }

#pragma unroll
        for (int s = 1; s < 64; s <<= 1) {
            float psdt = __shfl_up(sdt, s, 64);
            float pl = __expf(-sdt);
            float pb[16];
#pragma unroll
            for (int n = 0; n < 16; n++) pb[n] = __shfl_up(Bp[n], s, 64);
            if (lane >= s) {
                float pw = pl;
#pragma unroll
                for (int n = 0; n < 16; n++) {
                    Bp[n] = pw * pb[n] + Bp[n];
                    pw *= pl;
                }
                sdt += psdt;
            }
        }

        if (lane == 63) {
            waggS[wv] = sdt;
#pragma unroll
            for (int n = 0; n < 16; n++) waggB[wv][n] = Bp[n];
        }
        __syncthreads();

        float exsdt = __shfl_up(sdt, 1, 64);
        float exB[16];
#pragma unroll
        for (int n = 0; n < 16; n++) exB[n] = __shfl_up(Bp[n], 1, 64);
        if (lane == 0) {
            exsdt = 0.f;
#pragma unroll
            for (int n = 0; n < 16; n++) exB[n] = 0.f;
        }
        float WB[16];
#pragma unroll
        for (int n = 0; n < 16; n++) WB[n] = 0.f;
        for (int ww = 0; ww < wv; ww++) {
            float plw = __expf(-waggS[ww]);
            float pww = plw;
#pragma unroll
            for (int n = 0; n < 16; n++) {
                WB[n] = pww * WB[n] + waggB[ww][n];
                pww *= plw;
            }
        }
        float pex = __expf(-exsdt);
        float pwx = pex;
#pragma unroll
        for (int n = 0; n < 16; n++) {
            h[n] = pwx * WB[n] + exB[n];
            pwx *= pex;
        }
    } else {
        // ======================= FALLBACK (exact) =======================
        float A[16];
#pragma unroll
        for (int n = 0; n < 16; n++) A[n] = -__expf(A_logs[dch * 16 + n]);
        float Ap[16], Bp[16];
        ushort8_t Bnx = *(const ushort8_t*)(bcb);
#pragma unroll
        for (int n = 0; n < 16; n++) {
            ushort8_t Bv = Bnx;
            if (n < 15) Bnx = *(const ushort8_t*)(bcb + (size_t)(n + 1) * 4096);
            float ap = 1.f, bp = 0.f, An = A[n];
#pragma unroll
            for (int i = 0; i < 8; i++) {
                float a = __expf(dtv[i] * An);
                bp = a * bp + dtu[i] * bf2f(Bv[i]);
                ap *= a;
            }
            Ap[n] = ap; Bp[n] = bp;
        }
#pragma unroll
        for (int s = 1; s < 64; s <<= 1) {
#pragma unroll
            for (int n = 0; n < 16; n++) {
                float pa = __shfl_up(Ap[n], s, 64);
                float pb = __shfl_up(Bp[n], s, 64);
                if (lane >= s) {
                    Bp[n] = Ap[n] * pb + Bp[n];
                    Ap[n] *= pa;
                }
            }
        }
        if (lane == 63) {
#pragma unroll
            for (int n = 0; n < 16; n++) { waggA[wv][n] = Ap[n]; waggB[wv][n] = Bp[n]; }
        }
        __syncthreads();
#pragma unroll
        for (int n = 0; n < 16; n++) {
            float exA = __shfl_up(Ap[n], 1, 64);
            float exB = __shfl_up(Bp[n], 1, 64);
            if (lane == 0) { exA = 1.f; exB = 0.f; }
            float WB = 0.f;
            for (int ww = 0; ww < wv; ww++)
                WB = waggA[ww][n] * WB + waggB[ww][n];
            h[n] = exA * WB + exB;
        }
    }

    // ---- pass 2: rescan with incoming state; B,C prefetched 1-deep
    if (intA) {
        float aw[8];
#pragma unroll
        for (int i = 0; i < 8; i++) aw[i] = av[i];
        ushort8_t Bnx = *(const ushort8_t*)(bcb);
        ushort8_t Cnx = *(const ushort8_t*)(bcb + (size_t)16 * 4096);
#pragma unroll
        for (int n = 0; n < 16; n++) {
            ushort8_t Bv = Bnx, Cv = Cnx;
            if (n < 15) {
                Bnx = *(const ushort8_t*)(bcb + (size_t)(n + 1) * 4096);
                Cnx = *(const ushort8_t*)(bcb + (size_t)(17 + n) * 4096);
            }
            float hn = h[n];
#pragma unroll
            for (int i = 0; i < 8; i++) {
                hn = aw[i] * hn + dtu[i] * bf2f(Bv[i]);
                ys[i] += hn * bf2f(Cv[i]);
            }
            if (n < 15) {
#pragma unroll
                for (int i = 0; i < 8; i++) aw[i] *= av[i];
            }
        }
    } else {
        ushort8_t Bnx = *(const ushort8_t*)(bcb);
        ushort8_t Cnx = *(const ushort8_t*)(bcb + (size_t)16 * 4096);
#pragma unroll
        for (int n = 0; n < 16; n++) {
            float An = -__expf(A_logs[dch * 16 + n]);
            ushort8_t Bv = Bnx, Cv = Cnx;
            if (n < 15) {
                Bnx = *(const ushort8_t*)(bcb + (size_t)(n + 1) * 4096);
                Cnx = *(const ushort8_t*)(bcb + (size_t)(17 + n) * 4096);
            }
            float hn = h[n];
#pragma unroll
            for (int i = 0; i < 8; i++) {
                float a = __expf(dtv[i] * An);
                hn = a * hn + dtu[i] * bf2f(Bv[i]);
                ys[i] += hn * bf2f(Cv[i]);
            }
        }
    }

    // ---- store y as bf16 (one 16B store)
    unsigned short* yo = y + (size_t)(b * 432 + dch) * 4096 + t * 8;
    ushort8_t o8;
#pragma unroll
    for (int i = 0; i < 8; i++) o8[i] = f2b(ys[i]);
    *(ushort8_t*)yo = o8;
}

// ---------------------------------------------------------------- MFMA tail
// fold GEMM (Wf[256][448]bf16 x Y[448][16]) -> LN -> gate -> out GEMM
// (Wo[128][256]bf16 x P[256][16]). 256 thr = 4 waves; 16 tokens/block.
// MFMA 16x16x32 bf16; D layout: col=lane&15 (token), row=(lane>>4)*4+reg.
__global__ void k_tail(const unsigned short* __restrict__ y, const float* __restrict__ zbuf,
                       const unsigned short* __restrict__ wfb, const float* __restrict__ ln_g,
                       const float* __restrict__ ln_b, const unsigned short* __restrict__ wob,
                       float* __restrict__ out) {
    int t = threadIdx.x;          // 0..255
    int w = t >> 6;               // wave 0..3
    int l = t & 63;               // lane
    int lc = l & 15;              // token (B col / D col)
    int lr = l >> 4;              // k-group / D row-group
    int tokbase = blockIdx.x * 16;
    int b = tokbase >> 12, lbase = tokbase & 4095;

    __shared__ unsigned short Yt[16][456];    // [tok][k] bf16 (k-pad 448, +8 bank pad)
    __shared__ unsigned short Pt[16][264];    // [tok][out] bf16 (+8 bank pad)
    __shared__ float red[4][16][2];

    // ---- stage Y transposed (rows d = t, t+256)
    for (int d = t; d < 448; d += 256) {
        if (d < 432) {
            const unsigned short* yr = y + (size_t)(b * 432 + d) * 4096 + lbase;
            ushort8_t v0 = *(const ushort8_t*)(yr);
            ushort8_t v1 = *(const ushort8_t*)(yr + 8);
#pragma unroll
            for (int j = 0; j < 8; j++) { Yt[j][d] = v0[j]; Yt[8 + j][d] = v1[j]; }
        } else {
#pragma unroll
            for (int j = 0; j < 16; j++) Yt[j][d] = 0;
        }
    }
    __syncthreads();

    // ---- fold GEMM: wave w owns M-tiles 4w..4w+3 (out rows), K=448 in 14 steps
    f32x4_t acc[4];
#pragma unroll
    for (int m = 0; m < 4; m++) acc[m] = (f32x4_t){0.f, 0.f, 0.f, 0.f};
    for (int ks = 0; ks < 14; ks++) {
        int kb = ks * 32 + lr * 8;
        short8_t bf = *(const short8_t*)&Yt[lc][kb];
#pragma unroll
        for (int m = 0; m < 4; m++) {
            int outrow = (4 * w + m) * 16 + lc;
            short8_t af = *(const short8_t*)(wfb + (size_t)outrow * 448 + kb);
            acc[m] = __builtin_amdgcn_mfma_f32_16x16x32_bf16(af, bf, acc[m], 0, 0, 0);
        }
    }

    // ---- LN stats per token (lane covers 16 outs for token lc)
    {
        float s = 0.f, s2 = 0.f;
#pragma unroll
        for (int m = 0; m < 4; m++) {
#pragma unroll
            for (int r = 0; r < 4; r++) { float v = acc[m][r]; s += v; s2 += v * v; }
        }
        s  += __shfl_xor(s, 16, 64);  s2 += __shfl_xor(s2, 16, 64);
        s  += __shfl_xor(s, 32, 64);  s2 += __shfl_xor(s2, 32, 64);
        if (l < 16) { red[w][l][0] = s; red[w][l][1] = s2; }
    }
    __syncthreads();
    float mu, rs;
    {
        float ts  = red[0][lc][0] + red[1][lc][0] + red[2][lc][0] + red[3][lc][0];
        float ts2 = red[0][lc][1] + red[1][lc][1] + red[2][lc][1] + red[3][lc][1];
        mu = ts * (1.f / 256.f);
        float var = ts2 * (1.f / 256.f) - mu * mu;
        rs = rsqrtf(var + 1e-5f);
    }

    // ---- LN + gate -> P (bf16) in LDS
#pragma unroll
    for (int m = 0; m < 4; m++) {
#pragma unroll
        for (int r = 0; r < 4; r++) {
            int oidx = (4 * w + m) * 16 + lr * 4 + r;
            float g = ln_g[oidx], be = ln_b[oidx];
            float zv = zbuf[(tokbase + lc) * 256 + oidx];
            float sz = zv / (1.f + __expf(-zv));
            float p = ((acc[m][r] - mu) * rs * g + be) * sz;
            Pt[lc][oidx] = f2b(p);
        }
    }
    __syncthreads();

    // ---- out GEMM: wave w owns M-tiles 2w, 2w+1 (128 outs), K=256 in 8 steps
    f32x4_t oacc[2];
    oacc[0] = (f32x4_t){0.f, 0.f, 0.f, 0.f};
    oacc[1] = (f32x4_t){0.f, 0.f, 0.f, 0.f};
    for (int ks = 0; ks < 8; ks++) {
        int kb = ks * 32 + lr * 8;
        short8_t bf = *(const short8_t*)&Pt[lc][kb];
#pragma unroll
        for (int m = 0; m < 2; m++) {
            int orow = (2 * w + m) * 16 + lc;
            short8_t af = *(const short8_t*)(wob + (size_t)orow * 256 + kb);
            oacc[m] = __builtin_amdgcn_mfma_f32_16x16x32_bf16(af, bf, oacc[m], 0, 0, 0);
        }
    }
    // store: token = lc, out = (2w+m)*16 + lr*4 + (0..3) -> float4
#pragma unroll
    for (int m = 0; m < 2; m++) {
        float o4[4];
#pragma unroll
        for (int r = 0; r < 4; r++) o4[r] = oacc[m][r];
        *(float4*)&out[(size_t)(tokbase + lc) * 128 + (2 * w + m) * 16 + lr * 4] = *(float4*)o4;
    }
}

// ---------------------------------------------------------------- launch
extern "C" void kernel_launch(void* const* d_in, const int* in_sizes, int n_in,
                              void* d_out, int out_size, void* d_ws, size_t ws_size,
                              hipStream_t stream) {
    const float* x        = (const float*)d_in[0];
    const float* w_in     = (const float*)d_in[1];
    const float* conv_w   = (const float*)d_in[2];
    const float* conv_b   = (const float*)d_in[3];
    const float* x_proj_w = (const float*)d_in[4];
    const float* dt_w     = (const float*)d_in[5];
    const float* dt_b     = (const float*)d_in[6];
    const float* A_logs   = (const float*)d_in[7];
    const float* Ds       = (const float*)d_in[8];
    const float* w_fold   = (const float*)d_in[9];
    const float* ln_g     = (const float*)d_in[10];
    const float* ln_b     = (const float*)d_in[11];
    const float* w_out    = (const float*)d_in[12];
    float* out = (float*)d_out;

    float* ws     = (float*)d_ws;
    float* xpt    = ws;                    // B*256*L        = 2,097,152
    float* zbuf   = xpt    + 2097152;      // NTOK*256       = 2,097,152
    float* xc     = zbuf   + 2097152;      // B*16*L         =   131,072
    float* dts    = xc     + 131072;       // B*14*L         =   114,688
    float* bc2    = dts    + 114688;       // B*32*L bf16    (float-sized slot)
    float* ybuf   = bc2    + 262144;       // B*432*L bf16   (float-sized slot)
    float* wint   = ybuf   + 3538944;      // 128*256 float2 =    65,536
    float* wfb    = wint   + 65536;        // 256*448 bf16   =    57,344 floats
    float* wob    = wfb    + 57344;        // 128*256 bf16   =    16,384 floats

    k_wprep<<<dim3(704), dim3(256), 0, stream>>>(w_in, w_fold, w_out, (float2*)wint,
                                                 (unsigned short*)wfb, (unsigned short*)wob);
    k_inproj<<<dim3(NTOK / 16), dim3(256), 0, stream>>>(x, (const float2*)wint, xpt, zbuf);
    k_conv<<<dim3(NTOK / 256, CCONV), dim3(256), 0, stream>>>(xpt, conv_w, conv_b, xc);
    k_xdbl<<<dim3(NTOK / 256, 23), dim3(256), 0, stream>>>(xc, x_proj_w, dts, (__hip_bfloat16*)bc2);
    k_scan<<<dim3(BATCH * DSEQ), dim3(512), 0, stream>>>(xc, dts, (const unsigned short*)bc2,
                                                         dt_w, dt_b, A_logs, Ds,
                                                         (unsigned short*)ybuf);
    k_tail<<<dim3(NTOK / 16), dim3(256), 0, stream>>>((const unsigned short*)ybuf, zbuf,
                                                      (const unsigned short*)wfb, ln_g, ln_b,
                                                      (const unsigned short*)wob, out);
}

// Round 23
// 142.277 us; speedup vs baseline: 1.5281x; 1.0393x over previous
//
#include <hip/hip_runtime.h>
#include <hip/hip_bf16.h>

// Problem constants
#define DM     128
#define DSTATE 16
#define DINNER 256
#define CCONV  16
#define NEIGH  27
#define DSEQ   432   // CCONV * NEIGH
#define DTRANK 14
#define LVOL   4096  // 16*16*16
#define BATCH  2
#define NTOK   8192  // BATCH * LVOL

typedef __attribute__((ext_vector_type(8))) unsigned short ushort8_t;
typedef __attribute__((ext_vector_type(8))) short short8_t;   // bf16x8 MFMA frag
typedef __attribute__((ext_vector_type(4))) float f32x4_t;    // MFMA acc

__device__ __forceinline__ float bf2f(unsigned short u) {
    union { unsigned int i; float f; } v; v.i = ((unsigned int)u) << 16; return v.f;
}
__device__ __forceinline__ unsigned short f2b(float f) {
    __hip_bfloat16 hb = __float2bfloat16(f);
    return *(unsigned short*)&hb;
}

// ---------------------------------------------------------------- merged weight prep
// wint2 (float2): [j][t]; wfb bf16 [256][448]; wob bf16 [128][256];
// wxpb bf16 [48][448] (x_proj_w zero-padded M 46->48, K 432->448)
__global__ void k_wprep(const float* __restrict__ w_in, const float* __restrict__ w_fold,
                        const float* __restrict__ w_out, const float* __restrict__ x_proj_w,
                        float2* __restrict__ wint2, unsigned short* __restrict__ wfb,
                        unsigned short* __restrict__ wob, unsigned short* __restrict__ wxpb) {
    int idx = blockIdx.x * 256 + threadIdx.x;
    if (idx < 32768) {
        int j = idx >> 8, t = idx & 255;
        wint2[idx] = make_float2(w_in[t * 128 + j], w_in[(t + 256) * 128 + j]);
    } else if (idx < 32768 + 114688) {
        int local = idx - 32768;
        int o = local / 448, dk = local - o * 448;
        wfb[local] = (dk < 432) ? f2b(w_fold[o * 432 + dk]) : (unsigned short)0;
    } else if (idx < 32768 + 114688 + 32768) {
        int local = idx - 32768 - 114688;
        wob[local] = f2b(w_out[local]);
    } else if (idx < 32768 + 114688 + 32768 + 21504) {
        int local = idx - 32768 - 114688 - 32768;
        int c = local / 448, dk = local - c * 448;
        wxpb[local] = (c < 46 && dk < 432) ? f2b(x_proj_w[c * 432 + dk]) : (unsigned short)0;
    }
}

// ---------------------------------------------------------------- in-proj GEMM
__global__ void k_inproj(const float* __restrict__ x, const float2* __restrict__ wint2,
                         float* __restrict__ xpt, float* __restrict__ zbuf) {
    int t = threadIdx.x;
    int tokbase = blockIdx.x * 16;
    int b = tokbase >> 12, lb = tokbase & 4095;
    __shared__ float xs_[16][128];
    for (int idx = t; idx < 2048; idx += 256)
        xs_[idx >> 7][idx & 127] = x[tokbase * 128 + idx];
    __syncthreads();
    float a0[16], a1[16];
#pragma unroll
    for (int k = 0; k < 16; k++) { a0[k] = 0.f; a1[k] = 0.f; }
    for (int j = 0; j < 128; j += 4) {
        float2 w0 = wint2[(j + 0) * 256 + t];
        float2 w1 = wint2[(j + 1) * 256 + t];
        float2 w2 = wint2[(j + 2) * 256 + t];
        float2 w3 = wint2[(j + 3) * 256 + t];
#pragma unroll
        for (int k = 0; k < 16; k++) {
            float4 xv = *(const float4*)&xs_[k][j];
            a0[k] += xv.x * w0.x + xv.y * w1.x + xv.z * w2.x + xv.w * w3.x;
            a1[k] += xv.x * w0.y + xv.y * w1.y + xv.z * w2.y + xv.w * w3.y;
        }
    }
    float* xr = xpt + (size_t)(b * 256 + t) * 4096 + lb;
#pragma unroll
    for (int k = 0; k < 16; k++) xr[k] = a0[k];
#pragma unroll
    for (int k = 0; k < 16; k++) zbuf[(tokbase + k) * 256 + t] = a1[k];
}

// ---------------------------------------------------------------- grouped conv3d + SiLU
// weights read directly from global (wave-uniform -> scalar loads, no LDS)
__global__ void k_conv(const float* __restrict__ xpt, const float* __restrict__ conv_w,
                       const float* __restrict__ conv_b, float* __restrict__ xc) {
    int t = threadIdx.x;
    int tok = blockIdx.x * 256 + t;
    int co = blockIdx.y;
    int b = tok >> 12, l = tok & 4095;
    int d0 = l >> 8, h0 = (l >> 4) & 15, w0 = l & 15;
    int nbo[27];
#pragma unroll
    for (int t27 = 0; t27 < 27; t27++) {
        int di = t27 / 9 - 1, dj = (t27 / 3) % 3 - 1, dk = t27 % 3 - 1;
        int zd = d0 + di, zh = h0 + dj, zw = w0 + dk;
        nbo[t27] = ((unsigned)zd > 15u || (unsigned)zh > 15u || (unsigned)zw > 15u)
                   ? -1 : ((zd << 8) + (zh << 4) + zw);
    }
    const float* xb = xpt + (size_t)(b * 256 + co * 16) * 4096;
    const float* wr = conv_w + co * 432;   // uniform -> s_load
    float acc0 = conv_b[co], acc1 = 0.f;
    for (int t27 = 0; t27 < 27; t27++) {
        int o = nbo[t27];
        if (o >= 0) {
#pragma unroll
            for (int q = 0; q < 16; q += 2) {
                acc0 += xb[q * 4096 + o]       * wr[q * 27 + t27];
                acc1 += xb[(q + 1) * 4096 + o] * wr[(q + 1) * 27 + t27];
            }
        }
    }
    float acc = acc0 + acc1;
    acc = acc / (1.f + __expf(-acc));  // SiLU
    xc[(b * 16 + co) * 4096 + l] = acc;
}

// ---------------------------------------------------------------- x_dbl via MFMA
// Stage unfold(xc) ONCE per 32 tokens into LDS bf16 [32][456], then
// W[48][448]bf16 x xsT -> 3 M-tiles x 2 N-tiles of mfma_f32_16x16x32_bf16.
// c<14 -> dts fp32; 14<=c<46 -> bc2 bf16.
__global__ void k_xdbl(const float* __restrict__ xc, const unsigned short* __restrict__ wxpb,
                       float* __restrict__ dts, __hip_bfloat16* __restrict__ bc2) {
    int t = threadIdx.x;          // 0..255, 4 waves
    int w = t >> 6, l = t & 63;
    int lc = l & 15, lr = l >> 4;
    int tokbase = blockIdx.x * 32;
    int b = tokbase >> 12, lbase = tokbase & 4095;

    __shared__ unsigned short xsT[32][456];

    // ---- stage: (ch,tap) pair per thread iter, 32 tokens each (coalesced in l)
    for (int p = t; p < 432; p += 256) {
        int ch = p / 27, tap = p - ch * 27;
        int di = tap / 9 - 1, dj = (tap / 3) % 3 - 1, dk = tap % 3 - 1;
        const float* xr = xc + (size_t)(b * 16 + ch) * 4096;
        for (int tk = 0; tk < 32; tk++) {
            int ll = lbase + tk;
            int zd = (ll >> 8) + di, zh = ((ll >> 4) & 15) + dj, zw = (ll & 15) + dk;
            float v = (((unsigned)zd <= 15u) && ((unsigned)zh <= 15u) && ((unsigned)zw <= 15u))
                      ? xr[(zd << 8) + (zh << 4) + zw] : 0.f;
            xsT[tk][p] = f2b(v);
        }
    }
    for (int idx = t; idx < 16 * 32; idx += 256)
        xsT[idx & 31][432 + (idx >> 5)] = 0;
    __syncthreads();

    // ---- MFMA: 6 tiles (mt 0..2, nt 0..1); wave w does ti = w, w+4
    for (int ti = w; ti < 6; ti += 4) {
        int mt = ti % 3, nt = ti / 3;
        f32x4_t acc = (f32x4_t){0.f, 0.f, 0.f, 0.f};
        for (int ks = 0; ks < 14; ks++) {
            int kb = ks * 32 + lr * 8;
            short8_t bfr = *(const short8_t*)&xsT[nt * 16 + lc][kb];
            short8_t afr = *(const short8_t*)(wxpb + (size_t)(mt * 16 + lc) * 448 + kb);
            acc = __builtin_amdgcn_mfma_f32_16x16x32_bf16(afr, bfr, acc, 0, 0, 0);
        }
        int ltok = lbase + nt * 16 + lc;
#pragma unroll
        for (int r = 0; r < 4; r++) {
            int c = mt * 16 + lr * 4 + r;
            if (c < 14)
                dts[(size_t)(b * 14 + c) * 4096 + ltok] = acc[r];
            else if (c < 46)
                bc2[(size_t)(b * 32 + (c - 14)) * 4096 + ltok] = __float2bfloat16(acc[r]);
        }
    }
}

// ---------------------------------------------------------------- selective scan (+ fused delta)
// Monoid (sdt, Bp[16]) fast path; bf16 y output. (R22 verified)
__global__ __launch_bounds__(512, 2) void k_scan(
        const float* __restrict__ xc, const float* __restrict__ dts,
        const unsigned short* __restrict__ bc2, const float* __restrict__ dt_w,
        const float* __restrict__ dt_b, const float* __restrict__ A_logs,
        const float* __restrict__ Ds, unsigned short* __restrict__ y) {
    int bd = blockIdx.x;
    int b = bd / 432, dch = bd % 432;
    int t = threadIdx.x;               // 0..511
    int lane = t & 63, wv = t >> 6;    // 8 waves

    bool intA = true;
#pragma unroll
    for (int n = 0; n < 16; n++) {
        float An = -__expf(A_logs[dch * 16 + n]);
        intA = intA && (fabsf(An + (float)(n + 1)) < 1e-3f);
    }
    float Dskip = Ds[dch];

    int cch = dch / 27, t27 = dch % 27;
    int di = t27 / 9 - 1, dj = (t27 / 3) % 3 - 1, dk = t27 % 3 - 1;

    // ---- fused delta: softplus(sum_r dts[b][r][l]*dt_w[dch][r] + dt_b[dch])
    float dtv[8];
    {
        float s[8];
        float bias = dt_b[dch];
#pragma unroll
        for (int i = 0; i < 8; i++) s[i] = bias;
        const float* dsb = dts + (size_t)(b * 14) * 4096 + t * 8;
#pragma unroll
        for (int r = 0; r < 14; r++) {
            float d8[8];
            *(float4*)&d8[0] = *(const float4*)(dsb + (size_t)r * 4096);
            *(float4*)&d8[4] = *(const float4*)(dsb + (size_t)r * 4096 + 4);
            float w = dt_w[dch * 14 + r];
#pragma unroll
            for (int i = 0; i < 8; i++) s[i] += d8[i] * w;
        }
#pragma unroll
        for (int i = 0; i < 8; i++)
            dtv[i] = (s[i] > 15.f) ? s[i] : log1pf(__expf(s[i]));
    }

    // ---- u gather; ys pre-init with Dskip*u
    int d0 = t >> 5, h0 = (t >> 1) & 15, w0 = (t & 1) << 3;
    int zd = d0 + di, zh = h0 + dj;
    bool rowok = ((unsigned)zd <= 15u) && ((unsigned)zh <= 15u);
    const float* xr = xc + (size_t)(b * 16 + cch) * 4096 + (zd << 8) + (zh << 4);
    float dtu[8], ys[8];
#pragma unroll
    for (int i = 0; i < 8; i++) {
        int zw = w0 + i + dk;
        float u = (rowok && (unsigned)zw <= 15u) ? xr[zw] : 0.f;
        dtu[i] = dtv[i] * u;
        ys[i] = Dskip * u;
    }

    const unsigned short* bcb = bc2 + (size_t)(b * 32) * 4096 + t * 8;

    __shared__ float waggA[8][16], waggB[8][16];
    __shared__ float waggS[8];

    float h[16];
    float av[8];

    if (intA) {
        // ======================= FAST PATH =======================
        float aw[8];
#pragma unroll
        for (int i = 0; i < 8; i++) { av[i] = __expf(-dtv[i]); aw[i] = av[i]; }
        float sdt = ((dtv[0] + dtv[1]) + (dtv[2] + dtv[3]))
                  + ((dtv[4] + dtv[5]) + (dtv[6] + dtv[7]));

        float Bp[16];
        {
            ushort8_t Bnx = *(const ushort8_t*)(bcb);
#pragma unroll
            for (int n = 0; n < 16; n++) {
                ushort8_t Bv = Bnx;
                if (n < 15) Bnx = *(const ushort8_t*)(bcb + (size_t)(n + 1) * 4096);
                float bp = 0.f;
#pragma unroll
                for (int i = 0; i < 8; i++)
                    bp = aw[i] * bp + dtu[i] * bf2f(Bv[i]);
                Bp[n] = bp;
                if (n < 15) {
#pragma unroll
                    for (int i = 0; i < 8; i++) aw[i] *= av[i];
                }
            }
        }

#pragma unroll
        for (int s = 1; s < 64; s <<= 1) {
            float psdt = __shfl_up(sdt, s, 64);
            float pl = __expf(-sdt);
            float pb[16];
#pragma unroll
            for (int n = 0; n < 16; n++) pb[n] = __shfl_up(Bp[n], s, 64);
            if (lane >= s) {
                float pw = pl;
#pragma unroll
                for (int n = 0; n < 16; n++) {
                    Bp[n] = pw * pb[n] + Bp[n];
                    pw *= pl;
                }
                sdt += psdt;
            }
        }

        if (lane == 63) {
            waggS[wv] = sdt;
#pragma unroll
            for (int n = 0; n < 16; n++) waggB[wv][n] = Bp[n];
        }
        __syncthreads();

        float exsdt = __shfl_up(sdt, 1, 64);
        float exB[16];
#pragma unroll
        for (int n = 0; n < 16; n++) exB[n] = __shfl_up(Bp[n], 1, 64);
        if (lane == 0) {
            exsdt = 0.f;
#pragma unroll
            for (int n = 0; n < 16; n++) exB[n] = 0.f;
        }
        float WB[16];
#pragma unroll
        for (int n = 0; n < 16; n++) WB[n] = 0.f;
        for (int ww = 0; ww < wv; ww++) {
            float plw = __expf(-waggS[ww]);
            float pww = plw;
#pragma unroll
            for (int n = 0; n < 16; n++) {
                WB[n] = pww * WB[n] + waggB[ww][n];
                pww *= plw;
            }
        }
        float pex = __expf(-exsdt);
        float pwx = pex;
#pragma unroll
        for (int n = 0; n < 16; n++) {
            h[n] = pwx * WB[n] + exB[n];
            pwx *= pex;
        }
    } else {
        // ======================= FALLBACK (exact) =======================
        float A[16];
#pragma unroll
        for (int n = 0; n < 16; n++) A[n] = -__expf(A_logs[dch * 16 + n]);
        float Ap[16], Bp[16];
        ushort8_t Bnx = *(const ushort8_t*)(bcb);
#pragma unroll
        for (int n = 0; n < 16; n++) {
            ushort8_t Bv = Bnx;
            if (n < 15) Bnx = *(const ushort8_t*)(bcb + (size_t)(n + 1) * 4096);
            float ap = 1.f, bp = 0.f, An = A[n];
#pragma unroll
            for (int i = 0; i < 8; i++) {
                float a = __expf(dtv[i] * An);
                bp = a * bp + dtu[i] * bf2f(Bv[i]);
                ap *= a;
            }
            Ap[n] = ap; Bp[n] = bp;
        }
#pragma unroll
        for (int s = 1; s < 64; s <<= 1) {
#pragma unroll
            for (int n = 0; n < 16; n++) {
                float pa = __shfl_up(Ap[n], s, 64);
                float pb = __shfl_up(Bp[n], s, 64);
                if (lane >= s) {
                    Bp[n] = Ap[n] * pb + Bp[n];
                    Ap[n] *= pa;
                }
            }
        }
        if (lane == 63) {
#pragma unroll
            for (int n = 0; n < 16; n++) { waggA[wv][n] = Ap[n]; waggB[wv][n] = Bp[n]; }
        }
        __syncthreads();
#pragma unroll
        for (int n = 0; n < 16; n++) {
            float exA = __shfl_up(Ap[n], 1, 64);
            float exB = __shfl_up(Bp[n], 1, 64);
            if (lane == 0) { exA = 1.f; exB = 0.f; }
            float WB = 0.f;
            for (int ww = 0; ww < wv; ww++)
                WB = waggA[ww][n] * WB + waggB[ww][n];
            h[n] = exA * WB + exB;
        }
    }

    // ---- pass 2: rescan with incoming state; B,C prefetched 1-deep
    if (intA) {
        float aw[8];
#pragma unroll
        for (int i = 0; i < 8; i++) aw[i] = av[i];
        ushort8_t Bnx = *(const ushort8_t*)(bcb);
        ushort8_t Cnx = *(const ushort8_t*)(bcb + (size_t)16 * 4096);
#pragma unroll
        for (int n = 0; n < 16; n++) {
            ushort8_t Bv = Bnx, Cv = Cnx;
            if (n < 15) {
                Bnx = *(const ushort8_t*)(bcb + (size_t)(n + 1) * 4096);
                Cnx = *(const ushort8_t*)(bcb + (size_t)(17 + n) * 4096);
            }
            float hn = h[n];
#pragma unroll
            for (int i = 0; i < 8; i++) {
                hn = aw[i] * hn + dtu[i] * bf2f(Bv[i]);
                ys[i] += hn * bf2f(Cv[i]);
            }
            if (n < 15) {
#pragma unroll
                for (int i = 0; i < 8; i++) aw[i] *= av[i];
            }
        }
    } else {
        ushort8_t Bnx = *(const ushort8_t*)(bcb);
        ushort8_t Cnx = *(const ushort8_t*)(bcb + (size_t)16 * 4096);
#pragma unroll
        for (int n = 0; n < 16; n++) {
            float An = -__expf(A_logs[dch * 16 + n]);
            ushort8_t Bv = Bnx, Cv = Cnx;
            if (n < 15) {
                Bnx = *(const ushort8_t*)(bcb + (size_t)(n + 1) * 4096);
                Cnx = *(const ushort8_t*)(bcb + (size_t)(17 + n) * 4096);
            }
            float hn = h[n];
#pragma unroll
            for (int i = 0; i < 8; i++) {
                float a = __expf(dtv[i] * An);
                hn = a * hn + dtu[i] * bf2f(Bv[i]);
                ys[i] += hn * bf2f(Cv[i]);
            }
        }
    }

    // ---- store y as bf16 (one 16B store)
    unsigned short* yo = y + (size_t)(b * 432 + dch) * 4096 + t * 8;
    ushort8_t o8;
#pragma unroll
    for (int i = 0; i < 8; i++) o8[i] = f2b(ys[i]);
    *(ushort8_t*)yo = o8;
}

// ---------------------------------------------------------------- MFMA tail (R22 verified)
__global__ void k_tail(const unsigned short* __restrict__ y, const float* __restrict__ zbuf,
                       const unsigned short* __restrict__ wfb, const float* __restrict__ ln_g,
                       const float* __restrict__ ln_b, const unsigned short* __restrict__ wob,
                       float* __restrict__ out) {
    int t = threadIdx.x;          // 0..255
    int w = t >> 6;               // wave 0..3
    int l = t & 63;               // lane
    int lc = l & 15;              // token (B col / D col)
    int lr = l >> 4;              // k-group / D row-group
    int tokbase = blockIdx.x * 16;
    int b = tokbase >> 12, lbase = tokbase & 4095;

    __shared__ unsigned short Yt[16][456];
    __shared__ unsigned short Pt[16][264];
    __shared__ float red[4][16][2];

    for (int d = t; d < 448; d += 256) {
        if (d < 432) {
            const unsigned short* yr = y + (size_t)(b * 432 + d) * 4096 + lbase;
            ushort8_t v0 = *(const ushort8_t*)(yr);
            ushort8_t v1 = *(const ushort8_t*)(yr + 8);
#pragma unroll
            for (int j = 0; j < 8; j++) { Yt[j][d] = v0[j]; Yt[8 + j][d] = v1[j]; }
        } else {
#pragma unroll
            for (int j = 0; j < 16; j++) Yt[j][d] = 0;
        }
    }
    __syncthreads();

    f32x4_t acc[4];
#pragma unroll
    for (int m = 0; m < 4; m++) acc[m] = (f32x4_t){0.f, 0.f, 0.f, 0.f};
    for (int ks = 0; ks < 14; ks++) {
        int kb = ks * 32 + lr * 8;
        short8_t bf = *(const short8_t*)&Yt[lc][kb];
#pragma unroll
        for (int m = 0; m < 4; m++) {
            int outrow = (4 * w + m) * 16 + lc;
            short8_t af = *(const short8_t*)(wfb + (size_t)outrow * 448 + kb);
            acc[m] = __builtin_amdgcn_mfma_f32_16x16x32_bf16(af, bf, acc[m], 0, 0, 0);
        }
    }

    {
        float s = 0.f, s2 = 0.f;
#pragma unroll
        for (int m = 0; m < 4; m++) {
#pragma unroll
            for (int r = 0; r < 4; r++) { float v = acc[m][r]; s += v; s2 += v * v; }
        }
        s  += __shfl_xor(s, 16, 64);  s2 += __shfl_xor(s2, 16, 64);
        s  += __shfl_xor(s, 32, 64);  s2 += __shfl_xor(s2, 32, 64);
        if (l < 16) { red[w][l][0] = s; red[w][l][1] = s2; }
    }
    __syncthreads();
    float mu, rs;
    {
        float ts  = red[0][lc][0] + red[1][lc][0] + red[2][lc][0] + red[3][lc][0];
        float ts2 = red[0][lc][1] + red[1][lc][1] + red[2][lc][1] + red[3][lc][1];
        mu = ts * (1.f / 256.f);
        float var = ts2 * (1.f / 256.f) - mu * mu;
        rs = rsqrtf(var + 1e-5f);
    }

#pragma unroll
    for (int m = 0; m < 4; m++) {
#pragma unroll
        for (int r = 0; r < 4; r++) {
            int oidx = (4 * w + m) * 16 + lr * 4 + r;
            float g = ln_g[oidx], be = ln_b[oidx];
            float zv = zbuf[(tokbase + lc) * 256 + oidx];
            float sz = zv / (1.f + __expf(-zv));
            float p = ((acc[m][r] - mu) * rs * g + be) * sz;
            Pt[lc][oidx] = f2b(p);
        }
    }
    __syncthreads();

    f32x4_t oacc[2];
    oacc[0] = (f32x4_t){0.f, 0.f, 0.f, 0.f};
    oacc[1] = (f32x4_t){0.f, 0.f, 0.f, 0.f};
    for (int ks = 0; ks < 8; ks++) {
        int kb = ks * 32 + lr * 8;
        short8_t bf = *(const short8_t*)&Pt[lc][kb];
#pragma unroll
        for (int m = 0; m < 2; m++) {
            int orow = (2 * w + m) * 16 + lc;
            short8_t af = *(const short8_t*)(wob + (size_t)orow * 256 + kb);
            oacc[m] = __builtin_amdgcn_mfma_f32_16x16x32_bf16(af, bf, oacc[m], 0, 0, 0);
        }
    }
#pragma unroll
    for (int m = 0; m < 2; m++) {
        float o4[4];
#pragma unroll
        for (int r = 0; r < 4; r++) o4[r] = oacc[m][r];
        *(float4*)&out[(size_t)(tokbase + lc) * 128 + (2 * w + m) * 16 + lr * 4] = *(float4*)o4;
    }
}

// ---------------------------------------------------------------- launch
extern "C" void kernel_launch(void* const* d_in, const int* in_sizes, int n_in,
                              void* d_out, int out_size, void* d_ws, size_t ws_size,
                              hipStream_t stream) {
    const float* x        = (const float*)d_in[0];
    const float* w_in     = (const float*)d_in[1];
    const float* conv_w   = (const float*)d_in[2];
    const float* conv_b   = (const float*)d_in[3];
    const float* x_proj_w = (const float*)d_in[4];
    const float* dt_w     = (const float*)d_in[5];
    const float* dt_b     = (const float*)d_in[6];
    const float* A_logs   = (const float*)d_in[7];
    const float* Ds       = (const float*)d_in[8];
    const float* w_fold   = (const float*)d_in[9];
    const float* ln_g     = (const float*)d_in[10];
    const float* ln_b     = (const float*)d_in[11];
    const float* w_out    = (const float*)d_in[12];
    float* out = (float*)d_out;

    float* ws     = (float*)d_ws;
    float* xpt    = ws;                    // B*256*L        = 2,097,152
    float* zbuf   = xpt    + 2097152;      // NTOK*256       = 2,097,152
    float* xc     = zbuf   + 2097152;      // B*16*L         =   131,072
    float* dts    = xc     + 131072;       // B*14*L         =   114,688
    float* bc2    = dts    + 114688;       // B*32*L bf16    (float-sized slot)
    float* ybuf   = bc2    + 262144;       // B*432*L bf16   (float-sized slot)
    float* wint   = ybuf   + 3538944;      // 128*256 float2 =    65,536
    float* wfb    = wint   + 65536;        // 256*448 bf16   =    57,344 floats
    float* wob    = wfb    + 57344;        // 128*256 bf16   =    16,384 floats
    float* wxpb   = wob    + 16384;        // 48*448 bf16    =    10,752 floats

    k_wprep<<<dim3(788), dim3(256), 0, stream>>>(w_in, w_fold, w_out, x_proj_w,
                                                 (float2*)wint, (unsigned short*)wfb,
                                                 (unsigned short*)wob, (unsigned short*)wxpb);
    k_inproj<<<dim3(NTOK / 16), dim3(256), 0, stream>>>(x, (const float2*)wint, xpt, zbuf);
    k_conv<<<dim3(NTOK / 256, CCONV), dim3(256), 0, stream>>>(xpt, conv_w, conv_b, xc);
    k_xdbl<<<dim3(NTOK / 32), dim3(256), 0, stream>>>(xc, (const unsigned short*)wxpb,
                                                      dts, (__hip_bfloat16*)bc2);
    k_scan<<<dim3(BATCH * DSEQ), dim3(512), 0, stream>>>(xc, dts, (const unsigned short*)bc2,
                                                         dt_w, dt_b, A_logs, Ds,
                                                         (unsigned short*)ybuf);
    k_tail<<<dim3(NTOK / 16), dim3(256), 0, stream>>>((const unsigned short*)ybuf, zbuf,
                                                      (const unsigned short*)wfb, ln_g, ln_b,
                                                      (const unsigned short*)wob, out);
}

// Round 24
// 127.315 us; speedup vs baseline: 1.7077x; 1.1175x over previous
//
#include <hip/hip_runtime.h>
#include <hip/hip_bf16.h>

// Problem constants
#define DM     128
#define DSTATE 16
#define DINNER 256
#define CCONV  16
#define NEIGH  27
#define DSEQ   432   // CCONV * NEIGH
#define DTRANK 14
#define LVOL   4096  // 16*16*16
#define BATCH  2
#define NTOK   8192  // BATCH * LVOL

typedef __attribute__((ext_vector_type(8))) unsigned short ushort8_t;
typedef __attribute__((ext_vector_type(8))) short short8_t;   // bf16x8 MFMA frag
typedef __attribute__((ext_vector_type(4))) float f32x4_t;    // MFMA acc

__device__ __forceinline__ float bf2f(unsigned short u) {
    union { unsigned int i; float f; } v; v.i = ((unsigned int)u) << 16; return v.f;
}
__device__ __forceinline__ unsigned short f2b(float f) {
    __hip_bfloat16 hb = __float2bfloat16(f);
    return *(unsigned short*)&hb;
}

// ---------------------------------------------------------------- merged weight prep
// wib bf16 [512][128]; wfb bf16 [256][448]; wob bf16 [128][256];
// wxpb bf16 [48][448] (x_proj_w zero-padded)
__global__ void k_wprep(const float* __restrict__ w_in, const float* __restrict__ w_fold,
                        const float* __restrict__ w_out, const float* __restrict__ x_proj_w,
                        unsigned short* __restrict__ wib, unsigned short* __restrict__ wfb,
                        unsigned short* __restrict__ wob, unsigned short* __restrict__ wxpb) {
    int idx = blockIdx.x * 256 + threadIdx.x;
    if (idx < 65536) {
        wib[idx] = f2b(w_in[idx]);
    } else if (idx < 65536 + 114688) {
        int local = idx - 65536;
        int o = local / 448, dk = local - o * 448;
        wfb[local] = (dk < 432) ? f2b(w_fold[o * 432 + dk]) : (unsigned short)0;
    } else if (idx < 65536 + 114688 + 32768) {
        int local = idx - 65536 - 114688;
        wob[local] = f2b(w_out[local]);
    } else if (idx < 65536 + 114688 + 32768 + 21504) {
        int local = idx - 65536 - 114688 - 32768;
        int c = local / 448, dk = local - c * 448;
        wxpb[local] = (c < 46 && dk < 432) ? f2b(x_proj_w[c * 432 + dk]) : (unsigned short)0;
    }
}

// ---------------------------------------------------------------- in-proj via MFMA
// X[32tok][128]bf16 x W[512][128]bf16 -> xp (ch-major xpt) + z (ch-major zbufT).
// 4 waves x 8 M-tiles x 2 N-tiles x 4 K-steps of mfma_f32_16x16x32_bf16.
__global__ void k_inproj(const float* __restrict__ x, const unsigned short* __restrict__ wib,
                         float* __restrict__ xpt, float* __restrict__ zbufT) {
    int t = threadIdx.x;          // 0..255
    int w = t >> 6, l = t & 63;
    int lc = l & 15, lr = l >> 4;
    int tokbase = blockIdx.x * 32;
    int b = tokbase >> 12, lbase = tokbase & 4095;

    __shared__ unsigned short xsT[32][136];   // [tok][k] bf16, +8 pad

    for (int idx = t; idx < 1024; idx += 256) {
        int row = idx >> 5, cb = idx & 31;
        float4 v = *(const float4*)(x + (size_t)(tokbase + row) * 128 + cb * 4);
        unsigned int p0 = (unsigned)f2b(v.x) | ((unsigned)f2b(v.y) << 16);
        unsigned int p1 = (unsigned)f2b(v.z) | ((unsigned)f2b(v.w) << 16);
        *(unsigned int*)&xsT[row][cb * 4]     = p0;
        *(unsigned int*)&xsT[row][cb * 4 + 2] = p1;
    }
    __syncthreads();

#pragma unroll
    for (int mi = 0; mi < 8; mi++) {
        int mt = w * 8 + mi;      // 0..31 (0..15 xp, 16..31 z)
#pragma unroll
        for (int nt = 0; nt < 2; nt++) {
            f32x4_t acc = (f32x4_t){0.f, 0.f, 0.f, 0.f};
#pragma unroll
            for (int ks = 0; ks < 4; ks++) {
                int kb = ks * 32 + lr * 8;
                short8_t bfr = *(const short8_t*)&xsT[nt * 16 + lc][kb];
                short8_t afr = *(const short8_t*)(wib + (size_t)(mt * 16 + lc) * 128 + kb);
                acc = __builtin_amdgcn_mfma_f32_16x16x32_bf16(afr, bfr, acc, 0, 0, 0);
            }
            int ltok = lbase + nt * 16 + lc;
            int ch = mt * 16 + lr * 4;
            float* dst = (mt < 16)
                ? (xpt   + (size_t)(b * 256 + ch)       * 4096 + ltok)
                : (zbufT + (size_t)(b * 256 + ch - 256) * 4096 + ltok);
#pragma unroll
            for (int r = 0; r < 4; r++)
                dst[(size_t)r * 4096] = acc[r];
        }
    }
}

// ---------------------------------------------------------------- grouped conv3d + SiLU
// weights read directly from global (wave-uniform -> scalar loads, no LDS)
__global__ void k_conv(const float* __restrict__ xpt, const float* __restrict__ conv_w,
                       const float* __restrict__ conv_b, float* __restrict__ xc) {
    int t = threadIdx.x;
    int tok = blockIdx.x * 256 + t;
    int co = blockIdx.y;
    int b = tok >> 12, l = tok & 4095;
    int d0 = l >> 8, h0 = (l >> 4) & 15, w0 = l & 15;
    int nbo[27];
#pragma unroll
    for (int t27 = 0; t27 < 27; t27++) {
        int di = t27 / 9 - 1, dj = (t27 / 3) % 3 - 1, dk = t27 % 3 - 1;
        int zd = d0 + di, zh = h0 + dj, zw = w0 + dk;
        nbo[t27] = ((unsigned)zd > 15u || (unsigned)zh > 15u || (unsigned)zw > 15u)
                   ? -1 : ((zd << 8) + (zh << 4) + zw);
    }
    const float* xb = xpt + (size_t)(b * 256 + co * 16) * 4096;
    const float* wr = conv_w + co * 432;   // uniform -> s_load
    float acc0 = conv_b[co], acc1 = 0.f;
    for (int t27 = 0; t27 < 27; t27++) {
        int o = nbo[t27];
        if (o >= 0) {
#pragma unroll
            for (int q = 0; q < 16; q += 2) {
                acc0 += xb[q * 4096 + o]       * wr[q * 27 + t27];
                acc1 += xb[(q + 1) * 4096 + o] * wr[(q + 1) * 27 + t27];
            }
        }
    }
    float acc = acc0 + acc1;
    acc = acc / (1.f + __expf(-acc));  // SiLU
    xc[(b * 16 + co) * 4096 + l] = acc;
}

// ---------------------------------------------------------------- x_dbl via MFMA (R23 verified)
__global__ void k_xdbl(const float* __restrict__ xc, const unsigned short* __restrict__ wxpb,
                       float* __restrict__ dts, __hip_bfloat16* __restrict__ bc2) {
    int t = threadIdx.x;          // 0..255, 4 waves
    int w = t >> 6, l = t & 63;
    int lc = l & 15, lr = l >> 4;
    int tokbase = blockIdx.x * 32;
    int b = tokbase >> 12, lbase = tokbase & 4095;

    __shared__ unsigned short xsT[32][456];

    for (int p = t; p < 432; p += 256) {
        int ch = p / 27, tap = p - ch * 27;
        int di = tap / 9 - 1, dj = (tap / 3) % 3 - 1, dk = tap % 3 - 1;
        const float* xr = xc + (size_t)(b * 16 + ch) * 4096;
        for (int tk = 0; tk < 32; tk++) {
            int ll = lbase + tk;
            int zd = (ll >> 8) + di, zh = ((ll >> 4) & 15) + dj, zw = (ll & 15) + dk;
            float v = (((unsigned)zd <= 15u) && ((unsigned)zh <= 15u) && ((unsigned)zw <= 15u))
                      ? xr[(zd << 8) + (zh << 4) + zw] : 0.f;
            xsT[tk][p] = f2b(v);
        }
    }
    for (int idx = t; idx < 16 * 32; idx += 256)
        xsT[idx & 31][432 + (idx >> 5)] = 0;
    __syncthreads();

    for (int ti = w; ti < 6; ti += 4) {
        int mt = ti % 3, nt = ti / 3;
        f32x4_t acc = (f32x4_t){0.f, 0.f, 0.f, 0.f};
        for (int ks = 0; ks < 14; ks++) {
            int kb = ks * 32 + lr * 8;
            short8_t bfr = *(const short8_t*)&xsT[nt * 16 + lc][kb];
            short8_t afr = *(const short8_t*)(wxpb + (size_t)(mt * 16 + lc) * 448 + kb);
            acc = __builtin_amdgcn_mfma_f32_16x16x32_bf16(afr, bfr, acc, 0, 0, 0);
        }
        int ltok = lbase + nt * 16 + lc;
#pragma unroll
        for (int r = 0; r < 4; r++) {
            int c = mt * 16 + lr * 4 + r;
            if (c < 14)
                dts[(size_t)(b * 14 + c) * 4096 + ltok] = acc[r];
            else if (c < 46)
                bc2[(size_t)(b * 32 + (c - 14)) * 4096 + ltok] = __float2bfloat16(acc[r]);
        }
    }
}

// ---------------------------------------------------------------- selective scan (+ fused delta)
// Monoid (sdt, Bp[16]) fast path; bf16 y output. (R22 verified)
__global__ __launch_bounds__(512, 2) void k_scan(
        const float* __restrict__ xc, const float* __restrict__ dts,
        const unsigned short* __restrict__ bc2, const float* __restrict__ dt_w,
        const float* __restrict__ dt_b, const float* __restrict__ A_logs,
        const float* __restrict__ Ds, unsigned short* __restrict__ y) {
    int bd = blockIdx.x;
    int b = bd / 432, dch = bd % 432;
    int t = threadIdx.x;               // 0..511
    int lane = t & 63, wv = t >> 6;    // 8 waves

    bool intA = true;
#pragma unroll
    for (int n = 0; n < 16; n++) {
        float An = -__expf(A_logs[dch * 16 + n]);
        intA = intA && (fabsf(An + (float)(n + 1)) < 1e-3f);
    }
    float Dskip = Ds[dch];

    int cch = dch / 27, t27 = dch % 27;
    int di = t27 / 9 - 1, dj = (t27 / 3) % 3 - 1, dk = t27 % 3 - 1;

    // ---- fused delta: softplus(sum_r dts[b][r][l]*dt_w[dch][r] + dt_b[dch])
    float dtv[8];
    {
        float s[8];
        float bias = dt_b[dch];
#pragma unroll
        for (int i = 0; i < 8; i++) s[i] = bias;
        const float* dsb = dts + (size_t)(b * 14) * 4096 + t * 8;
#pragma unroll
        for (int r = 0; r < 14; r++) {
            float d8[8];
            *(float4*)&d8[0] = *(const float4*)(dsb + (size_t)r * 4096);
            *(float4*)&d8[4] = *(const float4*)(dsb + (size_t)r * 4096 + 4);
            float w = dt_w[dch * 14 + r];
#pragma unroll
            for (int i = 0; i < 8; i++) s[i] += d8[i] * w;
        }
#pragma unroll
        for (int i = 0; i < 8; i++)
            dtv[i] = (s[i] > 15.f) ? s[i] : log1pf(__expf(s[i]));
    }

    // ---- u gather; ys pre-init with Dskip*u
    int d0 = t >> 5, h0 = (t >> 1) & 15, w0 = (t & 1) << 3;
    int zd = d0 + di, zh = h0 + dj;
    bool rowok = ((unsigned)zd <= 15u) && ((unsigned)zh <= 15u);
    const float* xr = xc + (size_t)(b * 16 + cch) * 4096 + (zd << 8) + (zh << 4);
    float dtu[8], ys[8];
#pragma unroll
    for (int i = 0; i < 8; i++) {
        int zw = w0 + i + dk;
        float u = (rowok && (unsigned)zw <= 15u) ? xr[zw] : 0.f;
        dtu[i] = dtv[i] * u;
        ys[i] = Dskip * u;
    }

    const unsigned short* bcb = bc2 + (size_t)(b * 32) * 4096 + t * 8;

    __shared__ float waggA[8][16], waggB[8][16];
    __shared__ float waggS[8];

    float h[16];
    float av[8];

    if (intA) {
        // ======================= FAST PATH =======================
        float aw[8];
#pragma unroll
        for (int i = 0; i < 8; i++) { av[i] = __expf(-dtv[i]); aw[i] = av[i]; }
        float sdt = ((dtv[0] + dtv[1]) + (dtv[2] + dtv[3]))
                  + ((dtv[4] + dtv[5]) + (dtv[6] + dtv[7]));

        float Bp[16];
        {
            ushort8_t Bnx = *(const ushort8_t*)(bcb);
#pragma unroll
            for (int n = 0; n < 16; n++) {
                ushort8_t Bv = Bnx;
                if (n < 15) Bnx = *(const ushort8_t*)(bcb + (size_t)(n + 1) * 4096);
                float bp = 0.f;
#pragma unroll
                for (int i = 0; i < 8; i++)
                    bp = aw[i] * bp + dtu[i] * bf2f(Bv[i]);
                Bp[n] = bp;
                if (n < 15) {
#pragma unroll
                    for (int i = 0; i < 8; i++) aw[i] *= av[i];
                }
            }
        }

#pragma unroll
        for (int s = 1; s < 64; s <<= 1) {
            float psdt = __shfl_up(sdt, s, 64);
            float pl = __expf(-sdt);
            float pb[16];
#pragma unroll
            for (int n = 0; n < 16; n++) pb[n] = __shfl_up(Bp[n], s, 64);
            if (lane >= s) {
                float pw = pl;
#pragma unroll
                for (int n = 0; n < 16; n++) {
                    Bp[n] = pw * pb[n] + Bp[n];
                    pw *= pl;
                }
                sdt += psdt;
            }
        }

        if (lane == 63) {
            waggS[wv] = sdt;
#pragma unroll
            for (int n = 0; n < 16; n++) waggB[wv][n] = Bp[n];
        }
        __syncthreads();

        float exsdt = __shfl_up(sdt, 1, 64);
        float exB[16];
#pragma unroll
        for (int n = 0; n < 16; n++) exB[n] = __shfl_up(Bp[n], 1, 64);
        if (lane == 0) {
            exsdt = 0.f;
#pragma unroll
            for (int n = 0; n < 16; n++) exB[n] = 0.f;
        }
        float WB[16];
#pragma unroll
        for (int n = 0; n < 16; n++) WB[n] = 0.f;
        for (int ww = 0; ww < wv; ww++) {
            float plw = __expf(-waggS[ww]);
            float pww = plw;
#pragma unroll
            for (int n = 0; n < 16; n++) {
                WB[n] = pww * WB[n] + waggB[ww][n];
                pww *= plw;
            }
        }
        float pex = __expf(-exsdt);
        float pwx = pex;
#pragma unroll
        for (int n = 0; n < 16; n++) {
            h[n] = pwx * WB[n] + exB[n];
            pwx *= pex;
        }
    } else {
        // ======================= FALLBACK (exact) =======================
        float A[16];
#pragma unroll
        for (int n = 0; n < 16; n++) A[n] = -__expf(A_logs[dch * 16 + n]);
        float Ap[16], Bp[16];
        ushort8_t Bnx = *(const ushort8_t*)(bcb);
#pragma unroll
        for (int n = 0; n < 16; n++) {
            ushort8_t Bv = Bnx;
            if (n < 15) Bnx = *(const ushort8_t*)(bcb + (size_t)(n + 1) * 4096);
            float ap = 1.f, bp = 0.f, An = A[n];
#pragma unroll
            for (int i = 0; i < 8; i++) {
                float a = __expf(dtv[i] * An);
                bp = a * bp + dtu[i] * bf2f(Bv[i]);
                ap *= a;
            }
            Ap[n] = ap; Bp[n] = bp;
        }
#pragma unroll
        for (int s = 1; s < 64; s <<= 1) {
#pragma unroll
            for (int n = 0; n < 16; n++) {
                float pa = __shfl_up(Ap[n], s, 64);
                float pb = __shfl_up(Bp[n], s, 64);
                if (lane >= s) {
                    Bp[n] = Ap[n] * pb + Bp[n];
                    Ap[n] *= pa;
                }
            }
        }
        if (lane == 63) {
#pragma unroll
            for (int n = 0; n < 16; n++) { waggA[wv][n] = Ap[n]; waggB[wv][n] = Bp[n]; }
        }
        __syncthreads();
#pragma unroll
        for (int n = 0; n < 16; n++) {
            float exA = __shfl_up(Ap[n], 1, 64);
            float exB = __shfl_up(Bp[n], 1, 64);
            if (lane == 0) { exA = 1.f; exB = 0.f; }
            float WB = 0.f;
            for (int ww = 0; ww < wv; ww++)
                WB = waggA[ww][n] * WB + waggB[ww][n];
            h[n] = exA * WB + exB;
        }
    }

    // ---- pass 2: rescan with incoming state; B,C prefetched 1-deep
    if (intA) {
        float aw[8];
#pragma unroll
        for (int i = 0; i < 8; i++) aw[i] = av[i];
        ushort8_t Bnx = *(const ushort8_t*)(bcb);
        ushort8_t Cnx = *(const ushort8_t*)(bcb + (size_t)16 * 4096);
#pragma unroll
        for (int n = 0; n < 16; n++) {
            ushort8_t Bv = Bnx, Cv = Cnx;
            if (n < 15) {
                Bnx = *(const ushort8_t*)(bcb + (size_t)(n + 1) * 4096);
                Cnx = *(const ushort8_t*)(bcb + (size_t)(17 + n) * 4096);
            }
            float hn = h[n];
#pragma unroll
            for (int i = 0; i < 8; i++) {
                hn = aw[i] * hn + dtu[i] * bf2f(Bv[i]);
                ys[i] += hn * bf2f(Cv[i]);
            }
            if (n < 15) {
#pragma unroll
                for (int i = 0; i < 8; i++) aw[i] *= av[i];
            }
        }
    } else {
        ushort8_t Bnx = *(const ushort8_t*)(bcb);
        ushort8_t Cnx = *(const ushort8_t*)(bcb + (size_t)16 * 4096);
#pragma unroll
        for (int n = 0; n < 16; n++) {
            float An = -__expf(A_logs[dch * 16 + n]);
            ushort8_t Bv = Bnx, Cv = Cnx;
            if (n < 15) {
                Bnx = *(const ushort8_t*)(bcb + (size_t)(n + 1) * 4096);
                Cnx = *(const ushort8_t*)(bcb + (size_t)(17 + n) * 4096);
            }
            float hn = h[n];
#pragma unroll
            for (int i = 0; i < 8; i++) {
                float a = __expf(dtv[i] * An);
                hn = a * hn + dtu[i] * bf2f(Bv[i]);
                ys[i] += hn * bf2f(Cv[i]);
            }
        }
    }

    // ---- store y as bf16 (one 16B store)
    unsigned short* yo = y + (size_t)(b * 432 + dch) * 4096 + t * 8;
    ushort8_t o8;
#pragma unroll
    for (int i = 0; i < 8; i++) o8[i] = f2b(ys[i]);
    *(ushort8_t*)yo = o8;
}

// ---------------------------------------------------------------- MFMA tail (R22 verified; z from zbufT ch-major)
__global__ void k_tail(const unsigned short* __restrict__ y, const float* __restrict__ zbufT,
                       const unsigned short* __restrict__ wfb, const float* __restrict__ ln_g,
                       const float* __restrict__ ln_b, const unsigned short* __restrict__ wob,
                       float* __restrict__ out) {
    int t = threadIdx.x;          // 0..255
    int w = t >> 6;               // wave 0..3
    int l = t & 63;               // lane
    int lc = l & 15;              // token (B col / D col)
    int lr = l >> 4;              // k-group / D row-group
    int tokbase = blockIdx.x * 16;
    int b = tokbase >> 12, lbase = tokbase & 4095;

    __shared__ unsigned short Yt[16][456];
    __shared__ unsigned short Pt[16][264];
    __shared__ float red[4][16][2];

    for (int d = t; d < 448; d += 256) {
        if (d < 432) {
            const unsigned short* yr = y + (size_t)(b * 432 + d) * 4096 + lbase;
            ushort8_t v0 = *(const ushort8_t*)(yr);
            ushort8_t v1 = *(const ushort8_t*)(yr + 8);
#pragma unroll
            for (int j = 0; j < 8; j++) { Yt[j][d] = v0[j]; Yt[8 + j][d] = v1[j]; }
        } else {
#pragma unroll
            for (int j = 0; j < 16; j++) Yt[j][d] = 0;
        }
    }
    __syncthreads();

    f32x4_t acc[4];
#pragma unroll
    for (int m = 0; m < 4; m++) acc[m] = (f32x4_t){0.f, 0.f, 0.f, 0.f};
    for (int ks = 0; ks < 14; ks++) {
        int kb = ks * 32 + lr * 8;
        short8_t bf = *(const short8_t*)&Yt[lc][kb];
#pragma unroll
        for (int m = 0; m < 4; m++) {
            int outrow = (4 * w + m) * 16 + lc;
            short8_t af = *(const short8_t*)(wfb + (size_t)outrow * 448 + kb);
            acc[m] = __builtin_amdgcn_mfma_f32_16x16x32_bf16(af, bf, acc[m], 0, 0, 0);
        }
    }

    {
        float s = 0.f, s2 = 0.f;
#pragma unroll
        for (int m = 0; m < 4; m++) {
#pragma unroll
            for (int r = 0; r < 4; r++) { float v = acc[m][r]; s += v; s2 += v * v; }
        }
        s  += __shfl_xor(s, 16, 64);  s2 += __shfl_xor(s2, 16, 64);
        s  += __shfl_xor(s, 32, 64);  s2 += __shfl_xor(s2, 32, 64);
        if (l < 16) { red[w][l][0] = s; red[w][l][1] = s2; }
    }
    __syncthreads();
    float mu, rs;
    {
        float ts  = red[0][lc][0] + red[1][lc][0] + red[2][lc][0] + red[3][lc][0];
        float ts2 = red[0][lc][1] + red[1][lc][1] + red[2][lc][1] + red[3][lc][1];
        mu = ts * (1.f / 256.f);
        float var = ts2 * (1.f / 256.f) - mu * mu;
        rs = rsqrtf(var + 1e-5f);
    }

#pragma unroll
    for (int m = 0; m < 4; m++) {
#pragma unroll
        for (int r = 0; r < 4; r++) {
            int oidx = (4 * w + m) * 16 + lr * 4 + r;
            float g = ln_g[oidx], be = ln_b[oidx];
            float zv = zbufT[(size_t)(b * 256 + oidx) * 4096 + lbase + lc];
            float sz = zv / (1.f + __expf(-zv));
            float p = ((acc[m][r] - mu) * rs * g + be) * sz;
            Pt[lc][oidx] = f2b(p);
        }
    }
    __syncthreads();

    f32x4_t oacc[2];
    oacc[0] = (f32x4_t){0.f, 0.f, 0.f, 0.f};
    oacc[1] = (f32x4_t){0.f, 0.f, 0.f, 0.f};
    for (int ks = 0; ks < 8; ks++) {
        int kb = ks * 32 + lr * 8;
        short8_t bf = *(const short8_t*)&Pt[lc][kb];
#pragma unroll
        for (int m = 0; m < 2; m++) {
            int orow = (2 * w + m) * 16 + lc;
            short8_t af = *(const short8_t*)(wob + (size_t)orow * 256 + kb);
            oacc[m] = __builtin_amdgcn_mfma_f32_16x16x32_bf16(af, bf, oacc[m], 0, 0, 0);
        }
    }
#pragma unroll
    for (int m = 0; m < 2; m++) {
        float o4[4];
#pragma unroll
        for (int r = 0; r < 4; r++) o4[r] = oacc[m][r];
        *(float4*)&out[(size_t)(tokbase + lc) * 128 + (2 * w + m) * 16 + lr * 4] = *(float4*)o4;
    }
}

// ---------------------------------------------------------------- launch
extern "C" void kernel_launch(void* const* d_in, const int* in_sizes, int n_in,
                              void* d_out, int out_size, void* d_ws, size_t ws_size,
                              hipStream_t stream) {
    const float* x        = (const float*)d_in[0];
    const float* w_in     = (const float*)d_in[1];
    const float* conv_w   = (const float*)d_in[2];
    const float* conv_b   = (const float*)d_in[3];
    const float* x_proj_w = (const float*)d_in[4];
    const float* dt_w     = (const float*)d_in[5];
    const float* dt_b     = (const float*)d_in[6];
    const float* A_logs   = (const float*)d_in[7];
    const float* Ds       = (const float*)d_in[8];
    const float* w_fold   = (const float*)d_in[9];
    const float* ln_g     = (const float*)d_in[10];
    const float* ln_b     = (const float*)d_in[11];
    const float* w_out    = (const float*)d_in[12];
    float* out = (float*)d_out;

    float* ws     = (float*)d_ws;
    float* xpt    = ws;                    // B*256*L        = 2,097,152
    float* zbufT  = xpt    + 2097152;      // B*256*L        = 2,097,152 (ch-major)
    float* xc     = zbufT  + 2097152;      // B*16*L         =   131,072
    float* dts    = xc     + 131072;       // B*14*L         =   114,688
    float* bc2    = dts    + 114688;       // B*32*L bf16    (float-sized slot)
    float* ybuf   = bc2    + 262144;       // B*432*L bf16   (float-sized slot)
    float* wib    = ybuf   + 3538944;      // 512*128 bf16   =    32,768 floats
    float* wfb    = wib    + 32768;        // 256*448 bf16   =    57,344 floats
    float* wob    = wfb    + 57344;        // 128*256 bf16   =    16,384 floats
    float* wxpb   = wob    + 16384;        // 48*448 bf16    =    10,752 floats

    k_wprep<<<dim3(916), dim3(256), 0, stream>>>(w_in, w_fold, w_out, x_proj_w,
                                                 (unsigned short*)wib, (unsigned short*)wfb,
                                                 (unsigned short*)wob, (unsigned short*)wxpb);
    k_inproj<<<dim3(NTOK / 32), dim3(256), 0, stream>>>(x, (const unsigned short*)wib,
                                                        xpt, zbufT);
    k_conv<<<dim3(NTOK / 256, CCONV), dim3(256), 0, stream>>>(xpt, conv_w, conv_b, xc);
    k_xdbl<<<dim3(NTOK / 32), dim3(256), 0, stream>>>(xc, (const unsigned short*)wxpb,
                                                      dts, (__hip_bfloat16*)bc2);
    k_scan<<<dim3(BATCH * DSEQ), dim3(512), 0, stream>>>(xc, dts, (const unsigned short*)bc2,
                                                         dt_w, dt_b, A_logs, Ds,
                                                         (unsigned short*)ybuf);
    k_tail<<<dim3(NTOK / 16), dim3(256), 0, stream>>>((const unsigned short*)ybuf, zbufT,
                                                      (const unsigned short*)wfb, ln_g, ln_b,
                                                      (const unsigned short*)wob, out);
}